// Round 1
// baseline (578.340 us; speedup 1.0000x reference)
//
#include <hip/hip_runtime.h>
#include <math.h>

// GlobalLocalAttention — fp32 baseline.
// Phases:
//  1. gemm_a: [l2_w; wq; wk; wv] @ x  -> G[b][1024][9216]
//  2. local_attn: 3x3 neighborhood attention + BN + bias -> localB
//  3. gemm_g: qkv_w @ x -> G[b][768][9216]   (reuses G region)
//  4. window_attn: 8x8 window MHA + rel-pos bias -> attnB
//  5. pool_combine: reflect-pad max/avg pools (H and W) + localB -> poolB
//  6. dw_bn: depthwise 8x8 conv (reflect+zero pad) + BN -> dwB
//  7. gemm_g: pw_w @ dwB -> d_out
// Workspace need: 23,592,960 floats = 94.4 MB.

namespace {

constexpr int NP = 96 * 96;       // 9216 pixels
constexpr int C  = 256;

// ---------------- GEMM core: C[mo0+i, n0+j] = sum_k W[m0+i, k] * X[k, n] ----
// K = 256 fixed, N = 9216 fixed. 128x128 tile, 256 threads, 8x8 per thread.
__device__ __forceinline__ void gemm_tile(
    const float* __restrict__ Wm, int m0,
    const float* __restrict__ Xb, float* __restrict__ Cb, int mo0, int n0,
    float (*As)[132], float (*Bs)[128])
{
  const int t  = threadIdx.x;
  const int tr = t >> 4;   // 0..15
  const int tc = t & 15;   // 0..15

  float acc[8][8];
#pragma unroll
  for (int i = 0; i < 8; ++i)
#pragma unroll
    for (int j = 0; j < 8; ++j) acc[i][j] = 0.f;

  for (int k0 = 0; k0 < 256; k0 += 16) {
    // A tile: 128 rows x 16 k  (512 float4 slots)
#pragma unroll
    for (int i = 0; i < 2; ++i) {
      int s   = i * 256 + t;
      int row = s >> 2, kq = s & 3;
      float4 v = *(const float4*)&Wm[(long)(m0 + row) * 256 + k0 + kq * 4];
      As[kq * 4 + 0][row] = v.x;
      As[kq * 4 + 1][row] = v.y;
      As[kq * 4 + 2][row] = v.z;
      As[kq * 4 + 3][row] = v.w;
    }
    // B tile: 16 k x 128 n
#pragma unroll
    for (int i = 0; i < 2; ++i) {
      int s  = i * 256 + t;
      int kk = s >> 5, nq = s & 31;
      float4 v = *(const float4*)&Xb[(long)(k0 + kk) * NP + n0 + nq * 4];
      *(float4*)&Bs[kk][nq * 4] = v;
    }
    __syncthreads();
#pragma unroll
    for (int k = 0; k < 16; ++k) {
      float a[8], bb[8];
#pragma unroll
      for (int e = 0; e < 8; ++e) a[e] = As[k][tr * 8 + e];
#pragma unroll
      for (int e = 0; e < 8; ++e) bb[e] = Bs[k][tc * 8 + e];
#pragma unroll
      for (int i = 0; i < 8; ++i)
#pragma unroll
        for (int j = 0; j < 8; ++j) acc[i][j] += a[i] * bb[j];
    }
    __syncthreads();
  }

#pragma unroll
  for (int i = 0; i < 8; ++i) {
    float4 v0 = {acc[i][0], acc[i][1], acc[i][2], acc[i][3]};
    float4 v1 = {acc[i][4], acc[i][5], acc[i][6], acc[i][7]};
    float* cp = &Cb[(long)(mo0 + tr * 8 + i) * NP + n0 + tc * 8];
    *(float4*)cp       = v0;
    *((float4*)cp + 1) = v1;
  }
}

// A-phase: 4 weight matrices (each 256x256) -> G rows [0,1024).
__global__ __launch_bounds__(256) void gemm_a(
    const float* __restrict__ w_l2, const float* __restrict__ w_q,
    const float* __restrict__ w_k,  const float* __restrict__ w_v,
    const float* __restrict__ X, float* __restrict__ Co)
{
  __shared__ float As[16][132];
  __shared__ float Bs[16][128];
  const int b  = blockIdx.z;
  const int rb = blockIdx.y;                    // 0..7 (128-row blocks)
  const float* Wm = (rb < 2) ? w_l2 : (rb < 4) ? w_q : (rb < 6) ? w_k : w_v;
  const int m0   = (rb & 1) * 128;
  const int mo0  = rb * 128;
  const float* Xb = X + (long)b * C * NP;
  float* Cb = Co + (long)b * 1024 * NP;
  gemm_tile(Wm, m0, Xb, Cb, mo0, blockIdx.x * 128, As, Bs);
}

// Generic single-weight GEMM (qkv: M=768, pw: M=256).
__global__ __launch_bounds__(256) void gemm_g(
    const float* __restrict__ Wm, const float* __restrict__ X,
    float* __restrict__ Co, long xBatch, long cBatch)
{
  __shared__ float As[16][132];
  __shared__ float Bs[16][128];
  const int b  = blockIdx.z;
  const int m0 = blockIdx.y * 128;
  gemm_tile(Wm, m0, X + (long)b * xBatch, Co + (long)b * cBatch, m0,
            blockIdx.x * 128, As, Bs);
}

// ---------------- 3x3 neighborhood attention + BN + bias -------------------
// G rows: [0,256)=l2out, [256,512)=q, [512,768)=k, [768,1024)=v  (per batch)
// Block: 256 threads = 64 pixels x 4 channel-chunks of 64.
__global__ __launch_bounds__(256) void local_attn(
    const float* __restrict__ G,
    const float* __restrict__ rel_x, const float* __restrict__ rel_y,
    const float* __restrict__ bn2_g, const float* __restrict__ bn2_b,
    const float* __restrict__ bn2_m, const float* __restrict__ bn2_v,
    const float* __restrict__ l1_bias, float* __restrict__ localO)
{
  const int b  = blockIdx.y;
  const int t  = threadIdx.x;
  const int px = t & 63;
  const int ch = t >> 6;                 // 0..3
  const int p  = blockIdx.x * 64 + px;
  const long gb = (long)b * 1024 * NP;
  const float* l2p = G + gb;
  const float* qp  = G + gb + (long)256 * NP;
  const float* kp  = G + gb + (long)512 * NP;
  const float* vp  = G + gb + (long)768 * NP;

  __shared__ float red[4][64][17];       // per-chunk partials: 9 logits + 3 rel
  __shared__ float srel[256 * 3];        // rel_x rows (c<128), rel_y rows (c>=128)
  __shared__ float sS[256], sO[256], sBias[256];

  if (t < 128) {
    srel[t * 3 + 0] = rel_x[t * 3 + 0];
    srel[t * 3 + 1] = rel_x[t * 3 + 1];
    srel[t * 3 + 2] = rel_x[t * 3 + 2];
  } else {
    int r = t - 128;
    srel[t * 3 + 0] = rel_y[r * 3 + 0];
    srel[t * 3 + 1] = rel_y[r * 3 + 1];
    srel[t * 3 + 2] = rel_y[r * 3 + 2];
  }
  {
    float s = bn2_g[t] * rsqrtf(bn2_v[t] + 1e-5f);
    sS[t] = s;
    sO[t] = bn2_b[t] - bn2_m[t] * s;
    sBias[t] = l1_bias[t];
  }

  const int h = p / 96, w = p % 96;
  int nof[9];
  float msk[9];
#pragma unroll
  for (int ky = 0; ky < 3; ++ky)
#pragma unroll
    for (int kx = 0; kx < 3; ++kx) {
      int j = ky * 3 + kx, hn = h + ky - 1, wn = w + kx - 1;
      bool v = (hn >= 0 && hn < 96 && wn >= 0 && wn < 96);
      nof[j] = v ? hn * 96 + wn : p;
      msk[j] = v ? 1.f : 0.f;
    }
  __syncthreads();

  float lg[9] = {0, 0, 0, 0, 0, 0, 0, 0, 0};
  float rq[3] = {0, 0, 0};
  const int c0 = ch * 64;
  for (int cc = 0; cc < 64; ++cc) {
    int c = c0 + cc;
    float qv = qp[(long)c * NP + p];
#pragma unroll
    for (int j = 0; j < 9; ++j) lg[j] += qv * (kp[(long)c * NP + nof[j]] * msk[j]);
#pragma unroll
    for (int l = 0; l < 3; ++l) rq[l] += qv * srel[c * 3 + l];
  }
#pragma unroll
  for (int j = 0; j < 9; ++j) red[ch][px][j] = lg[j];
#pragma unroll
  for (int l = 0; l < 3; ++l) red[ch][px][9 + l] = rq[l];
  __syncthreads();

  // every thread redundantly reduces + softmaxes its pixel's 9 logits
  float a[9];
  float mx = -1e30f;
#pragma unroll
  for (int j = 0; j < 9; ++j) {
    float v = red[0][px][j] + red[1][px][j] + red[2][px][j] + red[3][px][j];
    float qxl = red[0][px][9 + (j % 3)] + red[1][px][9 + (j % 3)];
    float qyk = red[2][px][9 + (j / 3)] + red[3][px][9 + (j / 3)];
    a[j] = v + qxl + qyk;
    mx = fmaxf(mx, a[j]);
  }
  float sum = 0.f;
#pragma unroll
  for (int j = 0; j < 9; ++j) { a[j] = __expf(a[j] - mx); sum += a[j]; }
  float inv = 1.f / sum;
#pragma unroll
  for (int j = 0; j < 9; ++j) a[j] *= inv;

  for (int cc = 0; cc < 64; ++cc) {
    int c = c0 + cc;
    float acc = 0.f;
#pragma unroll
    for (int j = 0; j < 9; ++j) acc += a[j] * (vp[(long)c * NP + nof[j]] * msk[j]);
    float l2v = l2p[(long)c * NP + p];
    localO[((long)b * C + c) * NP + p] = l2v * sS[c] + sO[c] + acc + sBias[c];
  }
}

// ---------------- 8x8 window attention -------------------------------------
// One block (64 threads = 1 wave) per (window, head, batch). d=16, scale=0.25.
__global__ __launch_bounds__(64) void window_attn(
    const float* __restrict__ G,          // [b][768][9216] (q|k|v, 256 each)
    const float* __restrict__ rel_table,  // 225 x 16
    float* __restrict__ attnO)            // [b][256][9216]
{
  const int win = blockIdx.x;   // 0..143
  const int hd  = blockIdx.y;   // 0..15
  const int b   = blockIdx.z;
  const int wy = win / 12, wx = win % 12;
  const float* base = G + (long)b * 768 * NP;

  __shared__ float sq[64 * 17], sk[64 * 17], sv[64 * 17];
  __shared__ float srpb[225];

  const int lane = threadIdx.x;
  const int ty = lane >> 3, tx = lane & 7;
  const int pix = (wy * 8 + ty) * 96 + wx * 8 + tx;

  for (int i = lane; i < 225; i += 64) srpb[i] = rel_table[i * 16 + hd];
#pragma unroll
  for (int d = 0; d < 16; ++d) {
    sq[lane * 17 + d] = base[(long)(hd * 16 + d) * NP + pix];
    sk[lane * 17 + d] = base[(long)(256 + hd * 16 + d) * NP + pix];
    sv[lane * 17 + d] = base[(long)(512 + hd * 16 + d) * NP + pix];
  }
  __syncthreads();

  float qreg[16];
#pragma unroll
  for (int d = 0; d < 16; ++d) qreg[d] = sq[lane * 17 + d];

  float dots[64];
#pragma unroll
  for (int j = 0; j < 64; ++j) {
    float s = 0.f;
#pragma unroll
    for (int d = 0; d < 16; ++d) s += qreg[d] * sk[j * 17 + d];
    int jy = j >> 3, jx = j & 7;
    dots[j] = s * 0.25f + srpb[(ty - jy + 7) * 15 + (tx - jx + 7)];
  }
  float m = dots[0];
#pragma unroll
  for (int j = 1; j < 64; ++j) m = fmaxf(m, dots[j]);
  float sum = 0.f;
#pragma unroll
  for (int j = 0; j < 64; ++j) { dots[j] = __expf(dots[j] - m); sum += dots[j]; }
  const float inv = 1.f / sum;

#pragma unroll
  for (int d = 0; d < 16; ++d) {
    float o = 0.f;
#pragma unroll
    for (int j = 0; j < 64; ++j) o += dots[j] * sv[j * 17 + d];
    attnO[((long)b * C + hd * 16 + d) * NP + pix] = o * inv;
  }
}

// ---------------- pools (reflect H/W pad) + combine with local -------------
__global__ __launch_bounds__(256) void pool_combine(
    const float* __restrict__ attn, const float* __restrict__ localO,
    float* __restrict__ outp)
{
  const int c = blockIdx.y, b = blockIdx.z;
  const int p = blockIdx.x * 256 + threadIdx.x;
  const int h = p / 96, w = p % 96;
  const float* A = attn + ((long)b * C + c) * NP;
  float mph = -1e30f, aph = 0.f, mpw = -1e30f, apw = 0.f;
#pragma unroll
  for (int i = 0; i < 8; ++i) {
    int r = h - 3 + i;
    if (r >= 0 && r <= 96) {
      int rr = (r == 96) ? 94 : r;
      float v = A[rr * 96 + w];
      mph = fmaxf(mph, v);
      aph += v;
    }
    int s = w - 3 + i;
    if (s >= 0 && s <= 96) {
      int ss = (s == 96) ? 94 : s;
      float v = A[h * 96 + ss];
      mpw = fmaxf(mpw, v);
      apw += v;
    }
  }
  const long o = ((long)b * C + c) * NP + p;
  outp[o] = mph + mpw + (aph + apw) * 0.125f + localO[o];
}

// ---------------- depthwise 8x8 conv (reflect+zero pad) + BN ---------------
__global__ __launch_bounds__(256) void dw_bn(
    const float* __restrict__ src, const float* __restrict__ dww,
    const float* __restrict__ bnp_g, const float* __restrict__ bnp_b,
    const float* __restrict__ bnp_m, const float* __restrict__ bnp_v,
    float* __restrict__ dst)
{
  const int c = blockIdx.y, b = blockIdx.z;
  __shared__ float wgt[64];
  const int t = threadIdx.x;
  if (t < 64) wgt[t] = dww[c * 64 + t];
  __syncthreads();

  const int p = blockIdx.x * 256 + t;
  const int h = p / 96, w = p % 96;
  const float* S = src + ((long)b * C + c) * NP;
  float acc = 0.f;
#pragma unroll
  for (int i = 0; i < 8; ++i) {
    int r = h + i - 3;
    if (r < 0 || r > 96) continue;
    int rr = (r == 96) ? 94 : r;
#pragma unroll
    for (int j = 0; j < 8; ++j) {
      int s = w + j - 3;
      if (s < 0 || s > 96) continue;
      int ss = (s == 96) ? 94 : s;
      acc += wgt[i * 8 + j] * S[rr * 96 + ss];
    }
  }
  float sc = bnp_g[c] * rsqrtf(bnp_v[c] + 1e-5f);
  dst[((long)b * C + c) * NP + p] = (acc - bnp_m[c]) * sc + bnp_b[c];
}

}  // namespace

extern "C" void kernel_launch(void* const* d_in, const int* in_sizes, int n_in,
                              void* d_out, int out_size, void* d_ws, size_t ws_size,
                              hipStream_t stream) {
  const float* x         = (const float*)d_in[0];
  const float* qkv_w     = (const float*)d_in[1];
  const float* l2_w      = (const float*)d_in[2];
  const float* bn2_g     = (const float*)d_in[3];
  const float* bn2_b     = (const float*)d_in[4];
  const float* bn2_m     = (const float*)d_in[5];
  const float* bn2_v     = (const float*)d_in[6];
  const float* wq        = (const float*)d_in[7];
  const float* wk        = (const float*)d_in[8];
  const float* wv        = (const float*)d_in[9];
  const float* rel_x     = (const float*)d_in[10];
  const float* rel_y     = (const float*)d_in[11];
  const float* l1_bias   = (const float*)d_in[12];
  const float* rel_table = (const float*)d_in[13];
  const float* dw_w      = (const float*)d_in[14];
  const float* bnp_g     = (const float*)d_in[15];
  const float* bnp_b     = (const float*)d_in[16];
  const float* bnp_m     = (const float*)d_in[17];
  const float* bnp_v     = (const float*)d_in[18];
  const float* pw_w      = (const float*)d_in[19];
  float* out = (float*)d_out;
  float* ws  = (float*)d_ws;

  const long XB = (long)C * NP;  // 2,359,296

  // Workspace layout (floats). Total 23,592,960 floats = 94.4 MB.
  float* G      = ws;                  // [2][1024][9216] = 18,874,368  (phase A)
                                       // later: qkv [2][768][9216] = 14,155,776
  float* attnB  = ws + 14155776;       // 4,718,592 (fits tail of G region)
  float* localB = ws + 18874368;       // 4,718,592
  float* poolB  = ws;                  // reuse (G dead after window_attn)
  float* dwB    = ws + 4718592;        // reuse

  // 1. l2 | q | k | v  GEMMs (fused into one launch, 1152 blocks)
  gemm_a<<<dim3(72, 8, 2), 256, 0, stream>>>(l2_w, wq, wk, wv, x, G);

  // 2. neighborhood attention + BN + bias
  local_attn<<<dim3(144, 2), 256, 0, stream>>>(G, rel_x, rel_y, bn2_g, bn2_b,
                                               bn2_m, bn2_v, l1_bias, localB);

  // 3. qkv GEMM (reuses G region)
  gemm_g<<<dim3(72, 6, 2), 256, 0, stream>>>(qkv_w, x, G, XB, (long)768 * NP);

  // 4. window attention
  window_attn<<<dim3(144, 16, 2), 64, 0, stream>>>(G, rel_table, attnB);

  // 5. pools + combine
  pool_combine<<<dim3(36, 256, 2), 256, 0, stream>>>(attnB, localB, poolB);

  // 6. depthwise conv + BN
  dw_bn<<<dim3(36, 256, 2), 256, 0, stream>>>(poolB, dw_w, bnp_g, bnp_b, bnp_m,
                                              bnp_v, dwB);

  // 7. pointwise GEMM -> d_out
  gemm_g<<<dim3(72, 2, 2), 256, 0, stream>>>(pw_w, dwB, out, XB, (long)C * NP);
}

// Round 2
// 314.188 us; speedup vs baseline: 1.8407x; 1.8407x over previous
//
#include <hip/hip_runtime.h>
#include <math.h>

// GlobalLocalAttention — round 1: bf16-MFMA GEMMs + LDS-tiled dw/pool.
//
// Workspace (floats, total 23,592,960 = 94.4 MB, liveness-packed):
//  ph0  cvt_wa:    Wa bf16 (1024x256)  @F 18,874,368  (LOCAL region start)
//  ph1  gemm(Wa):  G = [l2|q|k|v]      @F [0, 18,874,368)
//  ph2  local_attn: LOCAL              @F [18,874,368, 23,592,960)  (kills Wa)
//  ph3  cvt_wqkv:  Wqkv bf16 (768x256) @F 14,155,776  (G dead after ph2)
//  ph4  gemm(Wqkv): QKV                @F [0, 14,155,776)
//  ph5  window_attn: ATTN              @F [14,155,776, 18,874,368) (kills Wqkv)
//  ph6  pool_combine: POOL             @F [0, 4,718,592)   (QKV dead)
//  ph7  dw_bn: DW                      @F [4,718,592, 9,437,184)
//  ph7.5 cvt_wpw:  Wpw bf16 (256x256)  @F 9,437,184
//  ph8  gemm(Wpw) -> d_out

namespace {

constexpr int NP = 96 * 96;   // 9216
constexpr int C  = 256;

typedef __bf16 bf16x8 __attribute__((ext_vector_type(8)));
typedef float  f32x4  __attribute__((ext_vector_type(4)));

__device__ __forceinline__ unsigned short f2bf_rne(float f) {
  unsigned u = __float_as_uint(f);
  u += 0x7FFFu + ((u >> 16) & 1u);
  return (unsigned short)(u >> 16);
}

// ---------------- weight conversion kernels --------------------------------
__global__ __launch_bounds__(256) void cvt_wa(
    const float* __restrict__ a, const float* __restrict__ b,
    const float* __restrict__ c, const float* __restrict__ d,
    unsigned short* __restrict__ dst)
{
  int i = blockIdx.x * 256 + threadIdx.x;            // 262,144 total
  int sel = i >> 16, j = i & 65535;
  const float* s = (sel == 0) ? a : (sel == 1) ? b : (sel == 2) ? c : d;
  dst[i] = f2bf_rne(s[j]);
}

__global__ __launch_bounds__(256) void cvt1(
    const float* __restrict__ s, unsigned short* __restrict__ dst, int n)
{
  int i = blockIdx.x * 256 + threadIdx.x;
  if (i < n) dst[i] = f2bf_rne(s[i]);
}

// ---------------- bf16 MFMA GEMM --------------------------------------------
// C[m][n] = sum_k W[m][k] * X[k][n];  K=256, N=9216.  W bf16, X fp32 (converted
// during staging).  128x128 tile, BK=32, 4 waves of 64x64, 16x16x32 MFMA.
// Fragment layout (m89-verified): A row=l&15, k=8*(l>>4)+j; B col=l&15,
// k=8*(l>>4)+j; D row=(l>>4)*4+r, col=l&15.
__global__ __launch_bounds__(256) void gemm_bf16(
    const unsigned short* __restrict__ W, const float* __restrict__ X,
    float* __restrict__ Co, long xStride, long cStride)
{
  __shared__ unsigned short As[128][40];   // [m][k], +8 pad (80B rows)
  __shared__ unsigned short Bs[128][40];   // [n][k], +8 pad

  const int t = threadIdx.x;
  const int lane = t & 63, wid = t >> 6;
  const int wm = wid >> 1, wn = wid & 1;
  const int l15 = lane & 15, l4 = lane >> 4;
  const int n0 = blockIdx.x * 128, m0 = blockIdx.y * 128;
  const float* Xb = X + (long)blockIdx.z * xStride;
  float* Cb = Co + (long)blockIdx.z * cStride;

  f32x4 acc[4][4];
#pragma unroll
  for (int i = 0; i < 4; ++i)
#pragma unroll
    for (int j = 0; j < 4; ++j) acc[i][j] = (f32x4){0.f, 0.f, 0.f, 0.f};

  for (int k0 = 0; k0 < 256; k0 += 32) {
#pragma unroll
    for (int i = 0; i < 2; ++i) {
      int s = i * 256 + t, m = s >> 2, kq = s & 3;
      *(uint4*)&As[m][kq * 8] =
          *(const uint4*)&W[(long)(m0 + m) * 256 + k0 + kq * 8];
    }
#pragma unroll
    for (int i = 0; i < 4; ++i) {
      int s = i * 256 + t, kk = s >> 5, nq = s & 31;
      float4 v = *(const float4*)&Xb[(long)(k0 + kk) * NP + n0 + nq * 4];
      Bs[nq * 4 + 0][kk] = f2bf_rne(v.x);
      Bs[nq * 4 + 1][kk] = f2bf_rne(v.y);
      Bs[nq * 4 + 2][kk] = f2bf_rne(v.z);
      Bs[nq * 4 + 3][kk] = f2bf_rne(v.w);
    }
    __syncthreads();

    bf16x8 af[4], bb[4];
#pragma unroll
    for (int mf = 0; mf < 4; ++mf)
      af[mf] = *(const bf16x8*)&As[wm * 64 + mf * 16 + l15][l4 * 8];
#pragma unroll
    for (int nf = 0; nf < 4; ++nf)
      bb[nf] = *(const bf16x8*)&Bs[wn * 64 + nf * 16 + l15][l4 * 8];
#pragma unroll
    for (int mf = 0; mf < 4; ++mf)
#pragma unroll
      for (int nf = 0; nf < 4; ++nf)
        acc[mf][nf] = __builtin_amdgcn_mfma_f32_16x16x32_bf16(
            af[mf], bb[nf], acc[mf][nf], 0, 0, 0);
    __syncthreads();
  }

#pragma unroll
  for (int mf = 0; mf < 4; ++mf)
#pragma unroll
    for (int r = 0; r < 4; ++r) {
      int row = m0 + wm * 64 + mf * 16 + l4 * 4 + r;
#pragma unroll
      for (int nf = 0; nf < 4; ++nf) {
        int col = n0 + wn * 64 + nf * 16 + l15;
        Cb[(long)row * NP + col] = acc[mf][nf][r];
      }
    }
}

// ---------------- 3x3 neighborhood attention + BN + bias -------------------
__global__ __launch_bounds__(256) void local_attn(
    const float* __restrict__ G,
    const float* __restrict__ rel_x, const float* __restrict__ rel_y,
    const float* __restrict__ bn2_g, const float* __restrict__ bn2_b,
    const float* __restrict__ bn2_m, const float* __restrict__ bn2_v,
    const float* __restrict__ l1_bias, float* __restrict__ localO)
{
  const int b  = blockIdx.y;
  const int t  = threadIdx.x;
  const int px = t & 63;
  const int ch = t >> 6;
  const int p  = blockIdx.x * 64 + px;
  const long gb = (long)b * 1024 * NP;
  const float* l2p = G + gb;
  const float* qp  = G + gb + (long)256 * NP;
  const float* kp  = G + gb + (long)512 * NP;
  const float* vp  = G + gb + (long)768 * NP;

  __shared__ float red[4][64][17];
  __shared__ float srel[256 * 3];
  __shared__ float sS[256], sO[256], sBias[256];

  if (t < 128) {
    srel[t * 3 + 0] = rel_x[t * 3 + 0];
    srel[t * 3 + 1] = rel_x[t * 3 + 1];
    srel[t * 3 + 2] = rel_x[t * 3 + 2];
  } else {
    int r = t - 128;
    srel[t * 3 + 0] = rel_y[r * 3 + 0];
    srel[t * 3 + 1] = rel_y[r * 3 + 1];
    srel[t * 3 + 2] = rel_y[r * 3 + 2];
  }
  {
    float s = bn2_g[t] * rsqrtf(bn2_v[t] + 1e-5f);
    sS[t] = s;
    sO[t] = bn2_b[t] - bn2_m[t] * s;
    sBias[t] = l1_bias[t];
  }

  const int h = p / 96, w = p % 96;
  int nof[9];
  float msk[9];
#pragma unroll
  for (int ky = 0; ky < 3; ++ky)
#pragma unroll
    for (int kx = 0; kx < 3; ++kx) {
      int j = ky * 3 + kx, hn = h + ky - 1, wn = w + kx - 1;
      bool v = (hn >= 0 && hn < 96 && wn >= 0 && wn < 96);
      nof[j] = v ? hn * 96 + wn : p;
      msk[j] = v ? 1.f : 0.f;
    }
  __syncthreads();

  float lg[9] = {0, 0, 0, 0, 0, 0, 0, 0, 0};
  float rq[3] = {0, 0, 0};
  const int c0 = ch * 64;
  for (int cc = 0; cc < 64; ++cc) {
    int c = c0 + cc;
    float qv = qp[(long)c * NP + p];
#pragma unroll
    for (int j = 0; j < 9; ++j) lg[j] += qv * (kp[(long)c * NP + nof[j]] * msk[j]);
#pragma unroll
    for (int l = 0; l < 3; ++l) rq[l] += qv * srel[c * 3 + l];
  }
#pragma unroll
  for (int j = 0; j < 9; ++j) red[ch][px][j] = lg[j];
#pragma unroll
  for (int l = 0; l < 3; ++l) red[ch][px][9 + l] = rq[l];
  __syncthreads();

  float a[9];
  float mx = -1e30f;
#pragma unroll
  for (int j = 0; j < 9; ++j) {
    float v = red[0][px][j] + red[1][px][j] + red[2][px][j] + red[3][px][j];
    float qxl = red[0][px][9 + (j % 3)] + red[1][px][9 + (j % 3)];
    float qyk = red[2][px][9 + (j / 3)] + red[3][px][9 + (j / 3)];
    a[j] = v + qxl + qyk;
    mx = fmaxf(mx, a[j]);
  }
  float sum = 0.f;
#pragma unroll
  for (int j = 0; j < 9; ++j) { a[j] = __expf(a[j] - mx); sum += a[j]; }
  float inv = 1.f / sum;
#pragma unroll
  for (int j = 0; j < 9; ++j) a[j] *= inv;

  for (int cc = 0; cc < 64; ++cc) {
    int c = c0 + cc;
    float acc = 0.f;
#pragma unroll
    for (int j = 0; j < 9; ++j) acc += a[j] * (vp[(long)c * NP + nof[j]] * msk[j]);
    float l2v = l2p[(long)c * NP + p];
    localO[((long)b * C + c) * NP + p] = l2v * sS[c] + sO[c] + acc + sBias[c];
  }
}

// ---------------- 8x8 window attention --------------------------------------
__global__ __launch_bounds__(64) void window_attn(
    const float* __restrict__ G, const float* __restrict__ rel_table,
    float* __restrict__ attnO)
{
  const int win = blockIdx.x;
  const int hd  = blockIdx.y;
  const int b   = blockIdx.z;
  const int wy = win / 12, wx = win % 12;
  const float* base = G + (long)b * 768 * NP;

  __shared__ float sq[64 * 17], sk[64 * 17], sv[64 * 17];
  __shared__ float srpb[225];

  const int lane = threadIdx.x;
  const int ty = lane >> 3, tx = lane & 7;
  const int pix = (wy * 8 + ty) * 96 + wx * 8 + tx;

  for (int i = lane; i < 225; i += 64) srpb[i] = rel_table[i * 16 + hd];
#pragma unroll
  for (int d = 0; d < 16; ++d) {
    sq[lane * 17 + d] = base[(long)(hd * 16 + d) * NP + pix];
    sk[lane * 17 + d] = base[(long)(256 + hd * 16 + d) * NP + pix];
    sv[lane * 17 + d] = base[(long)(512 + hd * 16 + d) * NP + pix];
  }
  __syncthreads();

  float qreg[16];
#pragma unroll
  for (int d = 0; d < 16; ++d) qreg[d] = sq[lane * 17 + d];

  float dots[64];
#pragma unroll
  for (int j = 0; j < 64; ++j) {
    float s = 0.f;
#pragma unroll
    for (int d = 0; d < 16; ++d) s += qreg[d] * sk[j * 17 + d];
    int jy = j >> 3, jx = j & 7;
    dots[j] = s * 0.25f + srpb[(ty - jy + 7) * 15 + (tx - jx + 7)];
  }
  float m = dots[0];
#pragma unroll
  for (int j = 1; j < 64; ++j) m = fmaxf(m, dots[j]);
  float sum = 0.f;
#pragma unroll
  for (int j = 0; j < 64; ++j) { dots[j] = __expf(dots[j] - m); sum += dots[j]; }
  const float inv = 1.f / sum;

#pragma unroll
  for (int d = 0; d < 16; ++d) {
    float o = 0.f;
#pragma unroll
    for (int j = 0; j < 64; ++j) o += dots[j] * sv[j * 17 + d];
    attnO[((long)b * C + hd * 16 + d) * NP + pix] = o * inv;
  }
}

// ---------------- pools + combine (LDS-tiled) -------------------------------
__global__ __launch_bounds__(256) void pool_combine(
    const float* __restrict__ attn, const float* __restrict__ localO,
    float* __restrict__ outp)
{
  const int cb = blockIdx.x;
  const int c = cb & 255, b = cb >> 8;
  __shared__ float img[96 * 97];
  const int t = threadIdx.x;
  const float* A = attn + ((long)b * C + c) * NP;
#pragma unroll
  for (int i = 0; i < 9; ++i) {
    int idx = i * 256 + t;                       // float4 index, 2304 total
    float4 v = ((const float4*)A)[idx];
    float* d = &img[(idx / 24) * 97 + (idx % 24) * 4];
    d[0] = v.x; d[1] = v.y; d[2] = v.z; d[3] = v.w;
  }
  __syncthreads();

  for (int p = t; p < NP; p += 256) {
    const int h = p / 96, w = p % 96;
    float mph = -1e30f, aph = 0.f, mpw = -1e30f, apw = 0.f;
#pragma unroll
    for (int i = 0; i < 8; ++i) {
      int r = h - 3 + i;
      if (r >= 0 && r <= 96) {
        int rr = (r == 96) ? 94 : r;
        float v = img[rr * 97 + w];
        mph = fmaxf(mph, v); aph += v;
      }
      int s = w - 3 + i;
      if (s >= 0 && s <= 96) {
        int ss = (s == 96) ? 94 : s;
        float v = img[h * 97 + ss];
        mpw = fmaxf(mpw, v); apw += v;
      }
    }
    const long o = ((long)b * C + c) * NP + p;
    outp[o] = mph + mpw + (aph + apw) * 0.125f + localO[o];
  }
}

// ---------------- depthwise 8x8 conv + BN (LDS-tiled) -----------------------
__global__ __launch_bounds__(256) void dw_bn(
    const float* __restrict__ src, const float* __restrict__ dww,
    const float* __restrict__ bnp_g, const float* __restrict__ bnp_b,
    const float* __restrict__ bnp_m, const float* __restrict__ bnp_v,
    float* __restrict__ dst)
{
  const int cb = blockIdx.x;
  const int c = cb & 255, b = cb >> 8;
  __shared__ float img[96 * 97];
  const int t = threadIdx.x;
  const float* S = src + ((long)b * C + c) * NP;
#pragma unroll
  for (int i = 0; i < 9; ++i) {
    int idx = i * 256 + t;
    float4 v = ((const float4*)S)[idx];
    float* d = &img[(idx / 24) * 97 + (idx % 24) * 4];
    d[0] = v.x; d[1] = v.y; d[2] = v.z; d[3] = v.w;
  }
  float wr[64];
#pragma unroll
  for (int i = 0; i < 64; ++i) wr[i] = dww[c * 64 + i];   // uniform -> s_loads
  __syncthreads();

  const float sc  = bnp_g[c] * rsqrtf(bnp_v[c] + 1e-5f);
  const float off = bnp_b[c] - bnp_m[c] * sc;

  for (int seg = t; seg < 1152; seg += 256) {   // 12 x-segments, 96 rows
    const int h = seg / 12, w0 = (seg % 12) * 8;
    float acc[8] = {0, 0, 0, 0, 0, 0, 0, 0};
#pragma unroll
    for (int i = 0; i < 8; ++i) {
      int r = h + i - 3;
      if (r < 0 || r > 96) continue;
      int rr = (r == 96) ? 94 : r;
      float win[15];
#pragma unroll
      for (int jj = 0; jj < 15; ++jj) {
        int cc = w0 + jj - 3;
        win[jj] = (cc >= 0 && cc <= 96) ? img[rr * 97 + ((cc == 96) ? 94 : cc)]
                                        : 0.f;
      }
#pragma unroll
      for (int j = 0; j < 8; ++j)
#pragma unroll
        for (int jj = 0; jj < 8; ++jj)
          acc[j] = fmaf(wr[i * 8 + jj], win[j + jj], acc[j]);
    }
    const long o = ((long)b * C + c) * NP + h * 96 + w0;
#pragma unroll
    for (int j = 0; j < 8; ++j) dst[o + j] = acc[j] * sc + off;
  }
}

}  // namespace

extern "C" void kernel_launch(void* const* d_in, const int* in_sizes, int n_in,
                              void* d_out, int out_size, void* d_ws, size_t ws_size,
                              hipStream_t stream) {
  const float* x         = (const float*)d_in[0];
  const float* qkv_w     = (const float*)d_in[1];
  const float* l2_w      = (const float*)d_in[2];
  const float* bn2_g     = (const float*)d_in[3];
  const float* bn2_b     = (const float*)d_in[4];
  const float* bn2_m     = (const float*)d_in[5];
  const float* bn2_v     = (const float*)d_in[6];
  const float* wq        = (const float*)d_in[7];
  const float* wk        = (const float*)d_in[8];
  const float* wv        = (const float*)d_in[9];
  const float* rel_x     = (const float*)d_in[10];
  const float* rel_y     = (const float*)d_in[11];
  const float* l1_bias   = (const float*)d_in[12];
  const float* rel_table = (const float*)d_in[13];
  const float* dw_w      = (const float*)d_in[14];
  const float* bnp_g     = (const float*)d_in[15];
  const float* bnp_b     = (const float*)d_in[16];
  const float* bnp_m     = (const float*)d_in[17];
  const float* bnp_v     = (const float*)d_in[18];
  const float* pw_w      = (const float*)d_in[19];
  float* out = (float*)d_out;
  float* ws  = (float*)d_ws;

  const long XB = (long)C * NP;          // 2,359,296

  float* G      = ws;                    // [2][1024][9216] phase A; later QKV
  float* attnB  = ws + 14155776;         // 4,718,592
  float* localB = ws + 18874368;         // 4,718,592
  float* poolB  = ws;                    // reuse
  float* dwB    = ws + 4718592;          // reuse

  unsigned short* Wa   = (unsigned short*)(ws + 18874368);  // 1024x256 bf16
  unsigned short* Wqkv = (unsigned short*)(ws + 14155776);  // 768x256 bf16
  unsigned short* Wpw  = (unsigned short*)(ws + 9437184);   // 256x256 bf16

  // ph0: weights A -> bf16 (lives in LOCAL region until local_attn)
  cvt_wa<<<dim3(1024), 256, 0, stream>>>(l2_w, wq, wk, wv, Wa);

  // ph1: [l2|q|k|v] GEMM (bf16 MFMA)
  gemm_bf16<<<dim3(72, 8, 2), 256, 0, stream>>>(Wa, x, G, XB, (long)1024 * NP);

  // ph2: neighborhood attention + BN + bias
  local_attn<<<dim3(144, 2), 256, 0, stream>>>(G, rel_x, rel_y, bn2_g, bn2_b,
                                               bn2_m, bn2_v, l1_bias, localB);

  // ph3: qkv weights -> bf16 (into dead ATTN region head)
  cvt1<<<dim3(768), 256, 0, stream>>>(qkv_w, Wqkv, 768 * 256);

  // ph4: qkv GEMM
  gemm_bf16<<<dim3(72, 6, 2), 256, 0, stream>>>(Wqkv, x, G, XB, (long)768 * NP);

  // ph5: window attention
  window_attn<<<dim3(144, 16, 2), 64, 0, stream>>>(G, rel_table, attnB);

  // ph6: pools + combine
  pool_combine<<<dim3(512), 256, 0, stream>>>(attnB, localB, poolB);

  // ph7: depthwise conv + BN
  dw_bn<<<dim3(512), 256, 0, stream>>>(poolB, dw_w, bnp_g, bnp_b, bnp_m,
                                       bnp_v, dwB);

  // ph7.5: pw weights -> bf16
  cvt1<<<dim3(256), 256, 0, stream>>>(pw_w, Wpw, 256 * 256);

  // ph8: pointwise GEMM -> out
  gemm_bf16<<<dim3(72, 2, 2), 256, 0, stream>>>(Wpw, dwB, out, XB, XB);
}

// Round 3
// 276.507 us; speedup vs baseline: 2.0916x; 1.1363x over previous
//
#include <hip/hip_runtime.h>
#include <math.h>

// GlobalLocalAttention — round 2: MFMA window attention + transposed bf16 QKV.
//
// Workspace (floats, 23,592,960 total = 94.4 MB):
//  ph0  cvt_wa:   Wa bf16 (1024x256)   @F 18,874,368
//  ph1  gemm_a:   G fp32 [b][1024][NP] @F [0, 18,874,368)
//  ph2  local_attn: localB             @F [18,874,368, 23,592,960)  (kills Wa)
//  ph3  cvt_wqkv: Wqkv bf16 (768x256)  @F 10,000,000                (G dead)
//  ph4  gemm_tr:  QKV bf16 [b][9216][768] @F [0, 7,077,888)
//  ph5  window_attn_mfma: attnB fp32   @F [14,155,776, 18,874,368)
//  ph6  pool_combine: poolB            @F [0, 4,718,592)   (QKV dead)
//  ph7  dw_bn: dwB                     @F [4,718,592, 9,437,184)
//  ph7.5 cvt_wpw: Wpw bf16 (256x256)   @F 9,437,184
//  ph8  gemm_bf16(pw) -> d_out

namespace {

constexpr int NP = 96 * 96;   // 9216
constexpr int C  = 256;

typedef __bf16 bf16x4 __attribute__((ext_vector_type(4)));
typedef __bf16 bf16x8 __attribute__((ext_vector_type(8)));
typedef float  f32x4  __attribute__((ext_vector_type(4)));
typedef float  f32x16 __attribute__((ext_vector_type(16)));

__device__ __forceinline__ unsigned short f2bf_rne(float f) {
  unsigned u = __float_as_uint(f);
  u += 0x7FFFu + ((u >> 16) & 1u);
  return (unsigned short)(u >> 16);
}
__device__ __forceinline__ __bf16 f2bf16(float f) {
  unsigned short s = f2bf_rne(f);
  return *(__bf16*)&s;
}

// ---------------- weight conversion kernels --------------------------------
__global__ __launch_bounds__(256) void cvt_wa(
    const float* __restrict__ a, const float* __restrict__ b,
    const float* __restrict__ c, const float* __restrict__ d,
    unsigned short* __restrict__ dst)
{
  int i = blockIdx.x * 256 + threadIdx.x;
  int sel = i >> 16, j = i & 65535;
  const float* s = (sel == 0) ? a : (sel == 1) ? b : (sel == 2) ? c : d;
  dst[i] = f2bf_rne(s[j]);
}

__global__ __launch_bounds__(256) void cvt1(
    const float* __restrict__ s, unsigned short* __restrict__ dst, int n)
{
  int i = blockIdx.x * 256 + threadIdx.x;
  if (i < n) dst[i] = f2bf_rne(s[i]);
}

// ---------------- bf16 MFMA GEMM, fp32 [chan][pix] output ------------------
__global__ __launch_bounds__(256) void gemm_bf16(
    const unsigned short* __restrict__ W, const float* __restrict__ X,
    float* __restrict__ Co, long xStride, long cStride)
{
  __shared__ unsigned short As[128][40];
  __shared__ unsigned short Bs[128][40];

  const int t = threadIdx.x;
  const int lane = t & 63, wid = t >> 6;
  const int wm = wid >> 1, wn = wid & 1;
  const int l15 = lane & 15, l4 = lane >> 4;
  const int n0 = blockIdx.x * 128, m0 = blockIdx.y * 128;
  const float* Xb = X + (long)blockIdx.z * xStride;
  float* Cb = Co + (long)blockIdx.z * cStride;

  f32x4 acc[4][4];
#pragma unroll
  for (int i = 0; i < 4; ++i)
#pragma unroll
    for (int j = 0; j < 4; ++j) acc[i][j] = (f32x4){0.f, 0.f, 0.f, 0.f};

  for (int k0 = 0; k0 < 256; k0 += 32) {
#pragma unroll
    for (int i = 0; i < 2; ++i) {
      int s = i * 256 + t, m = s >> 2, kq = s & 3;
      *(uint4*)&As[m][kq * 8] =
          *(const uint4*)&W[(long)(m0 + m) * 256 + k0 + kq * 8];
    }
#pragma unroll
    for (int i = 0; i < 4; ++i) {
      int s = i * 256 + t, kk = s >> 5, nq = s & 31;
      float4 v = *(const float4*)&Xb[(long)(k0 + kk) * NP + n0 + nq * 4];
      Bs[nq * 4 + 0][kk] = f2bf_rne(v.x);
      Bs[nq * 4 + 1][kk] = f2bf_rne(v.y);
      Bs[nq * 4 + 2][kk] = f2bf_rne(v.z);
      Bs[nq * 4 + 3][kk] = f2bf_rne(v.w);
    }
    __syncthreads();

    bf16x8 af[4], bb[4];
#pragma unroll
    for (int mf = 0; mf < 4; ++mf)
      af[mf] = *(const bf16x8*)&As[wm * 64 + mf * 16 + l15][l4 * 8];
#pragma unroll
    for (int nf = 0; nf < 4; ++nf)
      bb[nf] = *(const bf16x8*)&Bs[wn * 64 + nf * 16 + l15][l4 * 8];
#pragma unroll
    for (int mf = 0; mf < 4; ++mf)
#pragma unroll
      for (int nf = 0; nf < 4; ++nf)
        acc[mf][nf] = __builtin_amdgcn_mfma_f32_16x16x32_bf16(
            af[mf], bb[nf], acc[mf][nf], 0, 0, 0);
    __syncthreads();
  }

#pragma unroll
  for (int mf = 0; mf < 4; ++mf)
#pragma unroll
    for (int r = 0; r < 4; ++r) {
      int row = m0 + wm * 64 + mf * 16 + l4 * 4 + r;
#pragma unroll
      for (int nf = 0; nf < 4; ++nf) {
        int col = n0 + wn * 64 + nf * 16 + l15;
        Cb[(long)row * NP + col] = acc[mf][nf][r];
      }
    }
}

// ---------------- bf16 MFMA GEMM, TRANSPOSED bf16 [pix][768] output --------
__global__ __launch_bounds__(256) void gemm_bf16_tr(
    const unsigned short* __restrict__ W, const float* __restrict__ X,
    unsigned short* __restrict__ Co, long xStride)
{
  __shared__ unsigned short As[128][40];
  __shared__ unsigned short Bs[128][40];
  __shared__ unsigned short tr[4][64][72];

  const int t = threadIdx.x;
  const int lane = t & 63, wid = t >> 6;
  const int wm = wid >> 1, wn = wid & 1;
  const int l15 = lane & 15, l4 = lane >> 4;
  const int n0 = blockIdx.x * 128, m0 = blockIdx.y * 128;
  const float* Xb = X + (long)blockIdx.z * xStride;
  unsigned short* Cb = Co + (long)blockIdx.z * 9216 * 768;

  f32x4 acc[4][4];
#pragma unroll
  for (int i = 0; i < 4; ++i)
#pragma unroll
    for (int j = 0; j < 4; ++j) acc[i][j] = (f32x4){0.f, 0.f, 0.f, 0.f};

  for (int k0 = 0; k0 < 256; k0 += 32) {
#pragma unroll
    for (int i = 0; i < 2; ++i) {
      int s = i * 256 + t, m = s >> 2, kq = s & 3;
      *(uint4*)&As[m][kq * 8] =
          *(const uint4*)&W[(long)(m0 + m) * 256 + k0 + kq * 8];
    }
#pragma unroll
    for (int i = 0; i < 4; ++i) {
      int s = i * 256 + t, kk = s >> 5, nq = s & 31;
      float4 v = *(const float4*)&Xb[(long)(k0 + kk) * NP + n0 + nq * 4];
      Bs[nq * 4 + 0][kk] = f2bf_rne(v.x);
      Bs[nq * 4 + 1][kk] = f2bf_rne(v.y);
      Bs[nq * 4 + 2][kk] = f2bf_rne(v.z);
      Bs[nq * 4 + 3][kk] = f2bf_rne(v.w);
    }
    __syncthreads();

    bf16x8 af[4], bb[4];
#pragma unroll
    for (int mf = 0; mf < 4; ++mf)
      af[mf] = *(const bf16x8*)&As[wm * 64 + mf * 16 + l15][l4 * 8];
#pragma unroll
    for (int nf = 0; nf < 4; ++nf)
      bb[nf] = *(const bf16x8*)&Bs[wn * 64 + nf * 16 + l15][l4 * 8];
#pragma unroll
    for (int mf = 0; mf < 4; ++mf)
#pragma unroll
      for (int nf = 0; nf < 4; ++nf)
        acc[mf][nf] = __builtin_amdgcn_mfma_f32_16x16x32_bf16(
            af[mf], bb[nf], acc[mf][nf], 0, 0, 0);
    __syncthreads();
  }

  // transpose epilogue: acc (chan-major) -> tr[wid][pix][chan] bf16
#pragma unroll
  for (int mf = 0; mf < 4; ++mf)
#pragma unroll
    for (int nf = 0; nf < 4; ++nf)
#pragma unroll
      for (int r = 0; r < 4; ++r)
        tr[wid][nf * 16 + l15][mf * 16 + l4 * 4 + r] = f2bf_rne(acc[mf][nf][r]);
  __syncthreads();

  const int pix = n0 + wn * 64 + lane;
  const long rowbase = (long)pix * 768 + m0 + wm * 64;
#pragma unroll
  for (int cc = 0; cc < 8; ++cc)
    *(uint4*)&Cb[rowbase + cc * 8] = *(const uint4*)&tr[wid][lane][cc * 8];
}

// ---------------- 3x3 neighborhood attention + BN + bias -------------------
__global__ __launch_bounds__(256) void local_attn(
    const float* __restrict__ G,
    const float* __restrict__ rel_x, const float* __restrict__ rel_y,
    const float* __restrict__ bn2_g, const float* __restrict__ bn2_b,
    const float* __restrict__ bn2_m, const float* __restrict__ bn2_v,
    const float* __restrict__ l1_bias, float* __restrict__ localO)
{
  const int b  = blockIdx.y;
  const int t  = threadIdx.x;
  const int px = t & 63;
  const int ch = t >> 6;
  const int p  = blockIdx.x * 64 + px;
  const long gb = (long)b * 1024 * NP;
  const float* l2p = G + gb;
  const float* qp  = G + gb + (long)256 * NP;
  const float* kp  = G + gb + (long)512 * NP;
  const float* vp  = G + gb + (long)768 * NP;

  __shared__ float red[4][64][17];
  __shared__ float srel[256 * 3];
  __shared__ float sS[256], sO[256], sBias[256];

  if (t < 128) {
    srel[t * 3 + 0] = rel_x[t * 3 + 0];
    srel[t * 3 + 1] = rel_x[t * 3 + 1];
    srel[t * 3 + 2] = rel_x[t * 3 + 2];
  } else {
    int r = t - 128;
    srel[t * 3 + 0] = rel_y[r * 3 + 0];
    srel[t * 3 + 1] = rel_y[r * 3 + 1];
    srel[t * 3 + 2] = rel_y[r * 3 + 2];
  }
  {
    float s = bn2_g[t] * rsqrtf(bn2_v[t] + 1e-5f);
    sS[t] = s;
    sO[t] = bn2_b[t] - bn2_m[t] * s;
    sBias[t] = l1_bias[t];
  }

  const int h = p / 96, w = p % 96;
  int nof[9];
  float msk[9];
#pragma unroll
  for (int ky = 0; ky < 3; ++ky)
#pragma unroll
    for (int kx = 0; kx < 3; ++kx) {
      int j = ky * 3 + kx, hn = h + ky - 1, wn = w + kx - 1;
      bool v = (hn >= 0 && hn < 96 && wn >= 0 && wn < 96);
      nof[j] = v ? hn * 96 + wn : p;
      msk[j] = v ? 1.f : 0.f;
    }
  __syncthreads();

  float lg[9] = {0, 0, 0, 0, 0, 0, 0, 0, 0};
  float rq[3] = {0, 0, 0};
  const int c0 = ch * 64;
  for (int cc = 0; cc < 64; ++cc) {
    int c = c0 + cc;
    float qv = qp[(long)c * NP + p];
#pragma unroll
    for (int j = 0; j < 9; ++j) lg[j] += qv * (kp[(long)c * NP + nof[j]] * msk[j]);
#pragma unroll
    for (int l = 0; l < 3; ++l) rq[l] += qv * srel[c * 3 + l];
  }
#pragma unroll
  for (int j = 0; j < 9; ++j) red[ch][px][j] = lg[j];
#pragma unroll
  for (int l = 0; l < 3; ++l) red[ch][px][9 + l] = rq[l];
  __syncthreads();

  float a[9];
  float mx = -1e30f;
#pragma unroll
  for (int j = 0; j < 9; ++j) {
    float v = red[0][px][j] + red[1][px][j] + red[2][px][j] + red[3][px][j];
    float qxl = red[0][px][9 + (j % 3)] + red[1][px][9 + (j % 3)];
    float qyk = red[2][px][9 + (j / 3)] + red[3][px][9 + (j / 3)];
    a[j] = v + qxl + qyk;
    mx = fmaxf(mx, a[j]);
  }
  float sum = 0.f;
#pragma unroll
  for (int j = 0; j < 9; ++j) { a[j] = __expf(a[j] - mx); sum += a[j]; }
  float inv = 1.f / sum;
#pragma unroll
  for (int j = 0; j < 9; ++j) a[j] *= inv;

  for (int cc = 0; cc < 64; ++cc) {
    int c = c0 + cc;
    float acc = 0.f;
#pragma unroll
    for (int j = 0; j < 9; ++j) acc += a[j] * (vp[(long)c * NP + nof[j]] * msk[j]);
    float l2v = l2p[(long)c * NP + p];
    localO[((long)b * C + c) * NP + p] = l2v * sS[c] + sO[c] + acc + sBias[c];
  }
}

// ---------------- 8x8 window attention via MFMA ----------------------------
// One wave per (window, head, batch).  QKV bf16 [b][pix][768].
// S^T = K @ Q^T  (2x2 tiles of mfma_f32_32x32x16_bf16, K=16=d)
//   A=K: row=key=lane&31, k(d)=8*(lane>>5)+j ;  B=Q: col=query, same k
//   D: col=query=lane&31, row=key=(r&3)+8*(r>>2)+4*(lane>>5)
// softmax lane-local (32 keys/lane/query) + shfl_xor(32); P normalized bf16
// bounced via LDS.  O^T = V^T @ P  (4 qt x 2 kc of mfma_f32_16x16x32_bf16).
__global__ __launch_bounds__(64) void window_attn_mfma(
    const unsigned short* __restrict__ QKV,
    const float* __restrict__ rel_table, float* __restrict__ attnO)
{
  const int win = blockIdx.x, hd = blockIdx.y, b = blockIdx.z;
  const int wy = win / 12, wx = win % 12;
  const int lane = threadIdx.x;
  const int l15 = lane & 15, hi4 = lane >> 4;
  const int l31 = lane & 31, hi2 = lane >> 5;

  __shared__ float srpb[225];
  __shared__ __bf16 P[64][72];

  for (int i = lane; i < 225; i += 64) srpb[i] = rel_table[i * 16 + hd];

  const __bf16* base = (const __bf16*)QKV + (long)b * 9216 * 768;
  const int pixbase = (wy * 8) * 96 + wx * 8;   // + (i>>3)*96 + (i&7)

#define WPIX(i) (pixbase + ((i) >> 3) * 96 + ((i) & 7))

  // load K/Q fragments (one 16B load each)
  bf16x8 kf[2], qf[2];
#pragma unroll
  for (int kt = 0; kt < 2; ++kt)
    kf[kt] = *(const bf16x8*)&base[(long)WPIX(32 * kt + l31) * 768 + 256 +
                                   hd * 16 + hi2 * 8];
#pragma unroll
  for (int qt = 0; qt < 2; ++qt)
    qf[qt] = *(const bf16x8*)&base[(long)WPIX(32 * qt + l31) * 768 +
                                   hd * 16 + hi2 * 8];

  // V^T A-fragments for PV (scalar loads, issued early)
  bf16x8 vf[2];
#pragma unroll
  for (int kc = 0; kc < 2; ++kc)
#pragma unroll
    for (int j = 0; j < 8; ++j)
      vf[kc][j] = base[(long)WPIX(32 * kc + 8 * hi4 + j) * 768 + 512 +
                       hd * 16 + l15];

  f32x16 S[2][2];
#pragma unroll
  for (int kt = 0; kt < 2; ++kt)
#pragma unroll
    for (int qt = 0; qt < 2; ++qt)
#pragma unroll
      for (int r = 0; r < 16; ++r) S[kt][qt][r] = 0.f;

#pragma unroll
  for (int kt = 0; kt < 2; ++kt)
#pragma unroll
    for (int qt = 0; qt < 2; ++qt)
      S[kt][qt] = __builtin_amdgcn_mfma_f32_32x32x16_bf16(
          kf[kt], qf[qt], S[kt][qt], 0, 0, 0);

  __syncthreads();   // srpb visible (wave-sync, cheap)

  // scale + rel-pos bias, running max per query
  float mx[2] = {-1e30f, -1e30f};
#pragma unroll
  for (int kt = 0; kt < 2; ++kt)
#pragma unroll
    for (int r = 0; r < 16; ++r) {
      const int key = 32 * kt + (r & 3) + 8 * (r >> 2) + 4 * hi2;
      const int ky = key >> 3, kx = key & 7;
#pragma unroll
      for (int qt = 0; qt < 2; ++qt) {
        const int q = 32 * qt + l31;
        const int qy = q >> 3, qx = q & 7;
        float s = S[kt][qt][r] * 0.25f + srpb[(qy - ky + 7) * 15 + (qx - kx + 7)];
        S[kt][qt][r] = s;
        mx[qt] = fmaxf(mx[qt], s);
      }
    }
#pragma unroll
  for (int qt = 0; qt < 2; ++qt)
    mx[qt] = fmaxf(mx[qt], __shfl_xor(mx[qt], 32));

  float sum[2] = {0.f, 0.f};
#pragma unroll
  for (int kt = 0; kt < 2; ++kt)
#pragma unroll
    for (int qt = 0; qt < 2; ++qt)
#pragma unroll
      for (int r = 0; r < 16; ++r) {
        float e = __expf(S[kt][qt][r] - mx[qt]);
        S[kt][qt][r] = e;
        sum[qt] += e;
      }
#pragma unroll
  for (int qt = 0; qt < 2; ++qt) sum[qt] += __shfl_xor(sum[qt], 32);
  const float inv0 = 1.f / sum[0], inv1 = 1.f / sum[1];

  // write normalized P (bf16) to LDS: P[query][key]
#pragma unroll
  for (int qt = 0; qt < 2; ++qt) {
    const float inv = qt ? inv1 : inv0;
#pragma unroll
    for (int kt = 0; kt < 2; ++kt)
#pragma unroll
      for (int rq = 0; rq < 4; ++rq) {
        bf16x4 pk;
#pragma unroll
        for (int j = 0; j < 4; ++j) pk[j] = f2bf16(S[kt][qt][rq * 4 + j] * inv);
        *(bf16x4*)&P[32 * qt + l31][32 * kt + 8 * rq + 4 * hi2] = pk;
      }
  }
  __syncthreads();

  // O^T = V^T @ P
  f32x4 o[4];
#pragma unroll
  for (int qt4 = 0; qt4 < 4; ++qt4) o[qt4] = (f32x4){0.f, 0.f, 0.f, 0.f};
#pragma unroll
  for (int kc = 0; kc < 2; ++kc)
#pragma unroll
    for (int qt4 = 0; qt4 < 4; ++qt4) {
      bf16x8 pf = *(const bf16x8*)&P[16 * qt4 + l15][32 * kc + 8 * hi4];
      o[qt4] = __builtin_amdgcn_mfma_f32_16x16x32_bf16(vf[kc], pf, o[qt4], 0, 0, 0);
    }

#pragma unroll
  for (int qt4 = 0; qt4 < 4; ++qt4)
#pragma unroll
    for (int r = 0; r < 4; ++r) {
      const int q = 16 * qt4 + l15;
      attnO[((long)b * C + hd * 16 + 4 * hi4 + r) * NP + WPIX(q)] = o[qt4][r];
    }
#undef WPIX
}

// ---------------- pools + combine (LDS-tiled) -------------------------------
__global__ __launch_bounds__(256) void pool_combine(
    const float* __restrict__ attn, const float* __restrict__ localO,
    float* __restrict__ outp)
{
  const int cb = blockIdx.x;
  const int c = cb & 255, b = cb >> 8;
  __shared__ float img[96 * 97];
  const int t = threadIdx.x;
  const float* A = attn + ((long)b * C + c) * NP;
#pragma unroll
  for (int i = 0; i < 9; ++i) {
    int idx = i * 256 + t;
    float4 v = ((const float4*)A)[idx];
    float* d = &img[(idx / 24) * 97 + (idx % 24) * 4];
    d[0] = v.x; d[1] = v.y; d[2] = v.z; d[3] = v.w;
  }
  __syncthreads();

  for (int p = t; p < NP; p += 256) {
    const int h = p / 96, w = p % 96;
    float mph = -1e30f, aph = 0.f, mpw = -1e30f, apw = 0.f;
#pragma unroll
    for (int i = 0; i < 8; ++i) {
      int r = h - 3 + i;
      if (r >= 0 && r <= 96) {
        int rr = (r == 96) ? 94 : r;
        float v = img[rr * 97 + w];
        mph = fmaxf(mph, v); aph += v;
      }
      int s = w - 3 + i;
      if (s >= 0 && s <= 96) {
        int ss = (s == 96) ? 94 : s;
        float v = img[h * 97 + ss];
        mpw = fmaxf(mpw, v); apw += v;
      }
    }
    const long o = ((long)b * C + c) * NP + p;
    outp[o] = mph + mpw + (aph + apw) * 0.125f + localO[o];
  }
}

// ---------------- depthwise 8x8 conv + BN (LDS-tiled) -----------------------
__global__ __launch_bounds__(256) void dw_bn(
    const float* __restrict__ src, const float* __restrict__ dww,
    const float* __restrict__ bnp_g, const float* __restrict__ bnp_b,
    const float* __restrict__ bnp_m, const float* __restrict__ bnp_v,
    float* __restrict__ dst)
{
  const int cb = blockIdx.x;
  const int c = cb & 255, b = cb >> 8;
  __shared__ float img[96 * 97];
  const int t = threadIdx.x;
  const float* S = src + ((long)b * C + c) * NP;
#pragma unroll
  for (int i = 0; i < 9; ++i) {
    int idx = i * 256 + t;
    float4 v = ((const float4*)S)[idx];
    float* d = &img[(idx / 24) * 97 + (idx % 24) * 4];
    d[0] = v.x; d[1] = v.y; d[2] = v.z; d[3] = v.w;
  }
  float wr[64];
#pragma unroll
  for (int i = 0; i < 64; ++i) wr[i] = dww[c * 64 + i];
  __syncthreads();

  const float sc  = bnp_g[c] * rsqrtf(bnp_v[c] + 1e-5f);
  const float off = bnp_b[c] - bnp_m[c] * sc;

  for (int seg = t; seg < 1152; seg += 256) {
    const int h = seg / 12, w0 = (seg % 12) * 8;
    float acc[8] = {0, 0, 0, 0, 0, 0, 0, 0};
#pragma unroll
    for (int i = 0; i < 8; ++i) {
      int r = h + i - 3;
      if (r < 0 || r > 96) continue;
      int rr = (r == 96) ? 94 : r;
      float win[15];
#pragma unroll
      for (int jj = 0; jj < 15; ++jj) {
        int cc = w0 + jj - 3;
        win[jj] = (cc >= 0 && cc <= 96) ? img[rr * 97 + ((cc == 96) ? 94 : cc)]
                                        : 0.f;
      }
#pragma unroll
      for (int j = 0; j < 8; ++j)
#pragma unroll
        for (int jj = 0; jj < 8; ++jj)
          acc[j] = fmaf(wr[i * 8 + jj], win[j + jj], acc[j]);
    }
    const long o = ((long)b * C + c) * NP + h * 96 + w0;
#pragma unroll
    for (int j = 0; j < 8; ++j) dst[o + j] = acc[j] * sc + off;
  }
}

}  // namespace

extern "C" void kernel_launch(void* const* d_in, const int* in_sizes, int n_in,
                              void* d_out, int out_size, void* d_ws, size_t ws_size,
                              hipStream_t stream) {
  const float* x         = (const float*)d_in[0];
  const float* qkv_w     = (const float*)d_in[1];
  const float* l2_w      = (const float*)d_in[2];
  const float* bn2_g     = (const float*)d_in[3];
  const float* bn2_b     = (const float*)d_in[4];
  const float* bn2_m     = (const float*)d_in[5];
  const float* bn2_v     = (const float*)d_in[6];
  const float* wq        = (const float*)d_in[7];
  const float* wk        = (const float*)d_in[8];
  const float* wv        = (const float*)d_in[9];
  const float* rel_x     = (const float*)d_in[10];
  const float* rel_y     = (const float*)d_in[11];
  const float* l1_bias   = (const float*)d_in[12];
  const float* rel_table = (const float*)d_in[13];
  const float* dw_w      = (const float*)d_in[14];
  const float* bnp_g     = (const float*)d_in[15];
  const float* bnp_b     = (const float*)d_in[16];
  const float* bnp_m     = (const float*)d_in[17];
  const float* bnp_v     = (const float*)d_in[18];
  const float* pw_w      = (const float*)d_in[19];
  float* out = (float*)d_out;
  float* ws  = (float*)d_ws;

  const long XB = (long)C * NP;          // 2,359,296

  float* G      = ws;                    // fp32 [2][1024][NP] (ph1-2)
  float* localB = ws + 18874368;
  float* attnB  = ws + 14155776;
  float* poolB  = ws;
  float* dwB    = ws + 4718592;

  unsigned short* Wa   = (unsigned short*)(ws + 18874368);
  unsigned short* Wqkv = (unsigned short*)(ws + 10000000);
  unsigned short* Wpw  = (unsigned short*)(ws + 9437184);
  unsigned short* QKV  = (unsigned short*)ws;   // bf16 [2][9216][768] (ph4-5)

  // ph0: A-phase weights -> bf16
  cvt_wa<<<dim3(1024), 256, 0, stream>>>(l2_w, wq, wk, wv, Wa);

  // ph1: [l2|q|k|v] GEMM -> G fp32
  gemm_bf16<<<dim3(72, 8, 2), 256, 0, stream>>>(Wa, x, G, XB, (long)1024 * NP);

  // ph2: neighborhood attention + BN + bias
  local_attn<<<dim3(144, 2), 256, 0, stream>>>(G, rel_x, rel_y, bn2_g, bn2_b,
                                               bn2_m, bn2_v, l1_bias, localB);

  // ph3: qkv weights -> bf16
  cvt1<<<dim3(768), 256, 0, stream>>>(qkv_w, Wqkv, 768 * 256);

  // ph4: qkv GEMM -> QKV bf16 [b][pix][768]
  gemm_bf16_tr<<<dim3(72, 6, 2), 256, 0, stream>>>(Wqkv, x, QKV, XB);

  // ph5: window attention (MFMA)
  window_attn_mfma<<<dim3(144, 16, 2), 64, 0, stream>>>(QKV, rel_table, attnB);

  // ph6: pools + combine
  pool_combine<<<dim3(512), 256, 0, stream>>>(attnB, localB, poolB);

  // ph7: depthwise conv + BN
  dw_bn<<<dim3(512), 256, 0, stream>>>(poolB, dw_w, bnp_g, bnp_b, bnp_m,
                                       bnp_v, dwB);

  // ph7.5: pw weights -> bf16
  cvt1<<<dim3(256), 256, 0, stream>>>(pw_w, Wpw, 256 * 256);

  // ph8: pointwise GEMM -> out
  gemm_bf16<<<dim3(72, 2, 2), 256, 0, stream>>>(Wpw, dwB, out, XB, XB);
}

// Round 4
// 205.005 us; speedup vs baseline: 2.8211x; 1.3488x over previous
//
#include <hip/hip_runtime.h>
#include <math.h>

// GlobalLocalAttention — round 3: pixel-major bf16 everywhere.
//
// Pipeline:
//  1. xpose:   x fp32 [b][256][NP] -> XT bf16 [b][NP][256]
//  2. cvt_w7:  all weights -> W7 bf16 [2048][256]
//              rows: [0:256 l2 |256:512 qL |512:768 kL |768:1024 vL
//                     |1024:1792 qkv |1792:2048 pw]
//  3. gemm_bt(W7[0:1024])    -> GA bf16 [b][NP][1024]
//  4. local_attn2(GA)        -> localB fp32 [b][256][NP]
//  5. gemm_bt(W7[1024:1792]) -> GB bf16 [b][NP][768]   (over GA, dead)
//  6. window_attn_mfma(GB)   -> attnB fp32 [b][256][NP]
//  7. pool_dw (pool+combine+dwconv+BN fused) -> dwB fp32 [b][256][NP]
//  8. gemm_xf32(W7[1792:2048], dwB) -> d_out fp32
//
// Workspace layout (floats, 23,592,960 total):
//  GA   [0 .. 9,437,184)      (bf16, 2*9216*1024)
//  GB   [0 .. 7,077,888)      (bf16, 2*9216*768; after GA dead)
//  dwB  [0 .. 4,718,592)      (fp32; after GB dead)
//  localB [9,437,184 .. 14,155,776)
//  attnB  [14,155,776 .. 18,874,368)
//  W7     [20,971,520 .. 21,233,664)   (bf16 2048x256)
//  XT     [21,233,664 .. 23,592,960)   (bf16 2*9216*256)

namespace {

constexpr int NP = 96 * 96;   // 9216
constexpr int C  = 256;

typedef __bf16 bf16x8 __attribute__((ext_vector_type(8)));
typedef float  f32x4  __attribute__((ext_vector_type(4)));
typedef float  f32x16 __attribute__((ext_vector_type(16)));
typedef __bf16 bf16x4 __attribute__((ext_vector_type(4)));

__device__ __forceinline__ unsigned short f2bf_rne(float f) {
  unsigned u = __float_as_uint(f);
  u += 0x7FFFu + ((u >> 16) & 1u);
  return (unsigned short)(u >> 16);
}
__device__ __forceinline__ __bf16 f2bf16(float f) {
  unsigned short s = f2bf_rne(f);
  return *(__bf16*)&s;
}

// ---------------- x transpose: fp32 [c][pix] -> bf16 [pix][c] --------------
__global__ __launch_bounds__(256) void xpose(
    const float* __restrict__ x, unsigned short* __restrict__ XT)
{
  __shared__ float tile[64][65];
  const int t = threadIdx.x;
  const int p0 = blockIdx.x * 64, c0 = blockIdx.y * 64, b = blockIdx.z;
  const float* xb = x + (long)b * C * NP;
#pragma unroll
  for (int i = 0; i < 4; ++i) {
    int s = i * 256 + t;                 // 0..1023
    int c = s >> 4, p4 = s & 15;
    float4 v = *(const float4*)&xb[(long)(c0 + c) * NP + p0 + p4 * 4];
    tile[c][p4 * 4 + 0] = v.x;
    tile[c][p4 * 4 + 1] = v.y;
    tile[c][p4 * 4 + 2] = v.z;
    tile[c][p4 * 4 + 3] = v.w;
  }
  __syncthreads();
  unsigned short* XTb = XT + (long)b * NP * 256;
#pragma unroll
  for (int i = 0; i < 2; ++i) {
    int s = i * 256 + t;                 // 0..511
    int p = s >> 3, c8 = s & 7;
    unsigned short u[8];
#pragma unroll
    for (int e = 0; e < 8; ++e) u[e] = f2bf_rne(tile[c8 * 8 + e][p]);
    *(uint4*)&XTb[(long)(p0 + p) * 256 + c0 + c8 * 8] = *(const uint4*)u;
  }
}

// ---------------- all weights -> bf16 (one row per block) ------------------
__global__ __launch_bounds__(256) void cvt_w7(
    const float* __restrict__ l2, const float* __restrict__ q,
    const float* __restrict__ k,  const float* __restrict__ v,
    const float* __restrict__ qkv, const float* __restrict__ pw,
    unsigned short* __restrict__ W7)
{
  const int row = blockIdx.x;            // 0..2047
  const float* src; int r;
  if      (row <  256) { src = l2;  r = row; }
  else if (row <  512) { src = q;   r = row - 256; }
  else if (row <  768) { src = k;   r = row - 512; }
  else if (row < 1024) { src = v;   r = row - 768; }
  else if (row < 1792) { src = qkv; r = row - 1024; }
  else                 { src = pw;  r = row - 1792; }
  W7[row * 256 + threadIdx.x] = f2bf_rne(src[r * 256 + threadIdx.x]);
}

// ---------------- bf16 GEMM: W[M][256] x XT[pix][256]^T -> O[pix][M] bf16 --
// 128x128 tile, BK=32, 4 waves (2m x 2n) of 64x64, 16x16x32 MFMA.
// Staging is pure 16B loads + 16B LDS writes (conflict-free groups).
// Transpose epilogue aliased over As/Bs.
__global__ __launch_bounds__(256) void gemm_bt(
    const unsigned short* __restrict__ W, const unsigned short* __restrict__ XT,
    unsigned short* __restrict__ O, int Mstride)
{
  __shared__ __align__(16) char smem[36864];
  unsigned short (*As)[40] = reinterpret_cast<unsigned short(*)[40]>(smem);
  unsigned short (*Bs)[40] = reinterpret_cast<unsigned short(*)[40]>(smem + 10240);

  const int t = threadIdx.x;
  const int lane = t & 63, wid = t >> 6;
  const int wm = wid >> 1, wn = wid & 1;
  const int l15 = lane & 15, l4 = lane >> 4;
  const int n0 = blockIdx.x * 128, m0 = blockIdx.y * 128;
  const unsigned short* XTb = XT + (long)blockIdx.z * NP * 256;
  unsigned short* Ob = O + (long)blockIdx.z * NP * Mstride;

  f32x4 acc[4][4];
#pragma unroll
  for (int i = 0; i < 4; ++i)
#pragma unroll
    for (int j = 0; j < 4; ++j) acc[i][j] = (f32x4){0.f, 0.f, 0.f, 0.f};

  for (int k0 = 0; k0 < 256; k0 += 32) {
#pragma unroll
    for (int i = 0; i < 2; ++i) {
      int s = i * 256 + t, r = s >> 2, kc = s & 3;
      *(uint4*)&As[r][kc * 8] =
          *(const uint4*)&W[(long)(m0 + r) * 256 + k0 + kc * 8];
    }
#pragma unroll
    for (int i = 0; i < 2; ++i) {
      int s = i * 256 + t, r = s >> 2, kc = s & 3;
      *(uint4*)&Bs[r][kc * 8] =
          *(const uint4*)&XTb[(long)(n0 + r) * 256 + k0 + kc * 8];
    }
    __syncthreads();

    bf16x8 af[4], bb[4];
#pragma unroll
    for (int mf = 0; mf < 4; ++mf)
      af[mf] = *(const bf16x8*)&As[wm * 64 + mf * 16 + l15][l4 * 8];
#pragma unroll
    for (int nf = 0; nf < 4; ++nf)
      bb[nf] = *(const bf16x8*)&Bs[wn * 64 + nf * 16 + l15][l4 * 8];
#pragma unroll
    for (int mf = 0; mf < 4; ++mf)
#pragma unroll
      for (int nf = 0; nf < 4; ++nf)
        acc[mf][nf] = __builtin_amdgcn_mfma_f32_16x16x32_bf16(
            af[mf], bb[nf], acc[mf][nf], 0, 0, 0);
    __syncthreads();
  }

  // epilogue: per-wave 64pix x 64chan transpose via LDS (aliased over As/Bs)
  unsigned short* trw = (unsigned short*)smem + wid * 64 * 72;
#pragma unroll
  for (int mf = 0; mf < 4; ++mf)
#pragma unroll
    for (int nf = 0; nf < 4; ++nf) {
      unsigned u0 = (unsigned)f2bf_rne(acc[mf][nf][0]) |
                    ((unsigned)f2bf_rne(acc[mf][nf][1]) << 16);
      unsigned u1 = (unsigned)f2bf_rne(acc[mf][nf][2]) |
                    ((unsigned)f2bf_rne(acc[mf][nf][3]) << 16);
      uint2 uu; uu.x = u0; uu.y = u1;
      *(uint2*)&trw[(nf * 16 + l15) * 72 + mf * 16 + l4 * 4] = uu;
    }
  __syncthreads();

  const long pix = n0 + wn * 64 + lane;
  const long rowbase = pix * Mstride + m0 + wm * 64;
#pragma unroll
  for (int cc = 0; cc < 8; ++cc)
    *(uint4*)&Ob[rowbase + cc * 8] = *(const uint4*)&trw[lane * 72 + cc * 8];
}

// ---------------- 3x3 neighborhood attention + BN + bias (pixel-major) -----
// Block: 256 threads = 32 pixels x 8 channel-chunks of 32.  GA [pix][1024]:
// slots l2@0, q@256, k@512, v@768.
__global__ __launch_bounds__(256) void local_attn2(
    const unsigned short* __restrict__ GA,
    const float* __restrict__ rel_x, const float* __restrict__ rel_y,
    const float* __restrict__ bn2_g, const float* __restrict__ bn2_b,
    const float* __restrict__ bn2_m, const float* __restrict__ bn2_v,
    const float* __restrict__ l1_bias, float* __restrict__ localO)
{
  const int b = blockIdx.y, t = threadIdx.x;
  const int px = t & 31, ch = t >> 5;          // ch 0..7
  const int p = blockIdx.x * 32 + px;
  const unsigned short* Gb = GA + (long)b * NP * 1024;

  __shared__ float red[8][32][13];
  __shared__ float srel[256 * 3];
  __shared__ float sS[256], sO[256], sBias[256];

  if (t < 128) {
    srel[t * 3 + 0] = rel_x[t * 3 + 0];
    srel[t * 3 + 1] = rel_x[t * 3 + 1];
    srel[t * 3 + 2] = rel_x[t * 3 + 2];
  } else {
    int r = t - 128;
    srel[t * 3 + 0] = rel_y[r * 3 + 0];
    srel[t * 3 + 1] = rel_y[r * 3 + 1];
    srel[t * 3 + 2] = rel_y[r * 3 + 2];
  }
  {
    float s = bn2_g[t] * rsqrtf(bn2_v[t] + 1e-5f);
    sS[t] = s;
    sO[t] = bn2_b[t] - bn2_m[t] * s;
    sBias[t] = l1_bias[t];
  }

  const int h = p / 96, w = p % 96;
  int nof[9];
  float msk[9];
#pragma unroll
  for (int ky = 0; ky < 3; ++ky)
#pragma unroll
    for (int kx = 0; kx < 3; ++kx) {
      int j = ky * 3 + kx, hn = h + ky - 1, wn = w + kx - 1;
      bool v = (hn >= 0 && hn < 96 && wn >= 0 && wn < 96);
      nof[j] = v ? hn * 96 + wn : p;
      msk[j] = v ? 1.f : 0.f;
    }
  __syncthreads();

  float lg[9] = {0, 0, 0, 0, 0, 0, 0, 0, 0};
  float rq[3] = {0, 0, 0};
  const int c0 = ch * 32;
#pragma unroll
  for (int i = 0; i < 4; ++i) {
    const int c = c0 + i * 8;
    bf16x8 q8 = *(const bf16x8*)&Gb[(long)p * 1024 + 256 + c];
    float qv[8];
#pragma unroll
    for (int e = 0; e < 8; ++e) qv[e] = (float)q8[e];
#pragma unroll
    for (int j = 0; j < 9; ++j) {
      bf16x8 k8 = *(const bf16x8*)&Gb[(long)nof[j] * 1024 + 512 + c];
#pragma unroll
      for (int e = 0; e < 8; ++e) lg[j] += qv[e] * (float)k8[e];
    }
#pragma unroll
    for (int e = 0; e < 8; ++e) {
      const float* sr = &srel[(c + e) * 3];
      rq[0] += qv[e] * sr[0];
      rq[1] += qv[e] * sr[1];
      rq[2] += qv[e] * sr[2];
    }
  }
#pragma unroll
  for (int j = 0; j < 9; ++j) red[ch][px][j] = lg[j] * msk[j];
#pragma unroll
  for (int l = 0; l < 3; ++l) red[ch][px][9 + l] = rq[l];
  __syncthreads();

  float a[9];
  float mx = -1e30f;
#pragma unroll
  for (int j = 0; j < 9; ++j) {
    float v = 0.f;
#pragma unroll
    for (int u = 0; u < 8; ++u) v += red[u][px][j];
    float qxl = red[0][px][9 + j % 3] + red[1][px][9 + j % 3] +
                red[2][px][9 + j % 3] + red[3][px][9 + j % 3];
    float qyk = red[4][px][9 + j / 3] + red[5][px][9 + j / 3] +
                red[6][px][9 + j / 3] + red[7][px][9 + j / 3];
    a[j] = v + qxl + qyk;
    mx = fmaxf(mx, a[j]);
  }
  float sum = 0.f;
#pragma unroll
  for (int j = 0; j < 9; ++j) { a[j] = __expf(a[j] - mx); sum += a[j]; }
  const float inv = 1.f / sum;
  float am[9];
#pragma unroll
  for (int j = 0; j < 9; ++j) am[j] = a[j] * inv * msk[j];

#pragma unroll
  for (int i = 0; i < 4; ++i) {
    const int c = c0 + i * 8;
    bf16x8 l28 = *(const bf16x8*)&Gb[(long)p * 1024 + 0 + c];
    float o8[8] = {0, 0, 0, 0, 0, 0, 0, 0};
#pragma unroll
    for (int j = 0; j < 9; ++j) {
      bf16x8 v8 = *(const bf16x8*)&Gb[(long)nof[j] * 1024 + 768 + c];
#pragma unroll
      for (int e = 0; e < 8; ++e) o8[e] += am[j] * (float)v8[e];
    }
#pragma unroll
    for (int e = 0; e < 8; ++e) {
      const int cg = c + e;
      localO[((long)b * C + cg) * NP + p] =
          (float)l28[e] * sS[cg] + sO[cg] + o8[e] + sBias[cg];
    }
  }
}

// ---------------- 8x8 window attention via MFMA (GB [pix][768]) ------------
__global__ __launch_bounds__(64) void window_attn_mfma(
    const unsigned short* __restrict__ QKV,
    const float* __restrict__ rel_table, float* __restrict__ attnO)
{
  const int win = blockIdx.x, hd = blockIdx.y, b = blockIdx.z;
  const int wy = win / 12, wx = win % 12;
  const int lane = threadIdx.x;
  const int l15 = lane & 15, hi4 = lane >> 4;
  const int l31 = lane & 31, hi2 = lane >> 5;

  __shared__ float srpb[225];
  __shared__ __bf16 P[64][72];

  for (int i = lane; i < 225; i += 64) srpb[i] = rel_table[i * 16 + hd];

  const __bf16* base = (const __bf16*)QKV + (long)b * 9216 * 768;
  const int pixbase = (wy * 8) * 96 + wx * 8;

#define WPIX(i) (pixbase + ((i) >> 3) * 96 + ((i) & 7))

  bf16x8 kf[2], qf[2];
#pragma unroll
  for (int kt = 0; kt < 2; ++kt)
    kf[kt] = *(const bf16x8*)&base[(long)WPIX(32 * kt + l31) * 768 + 256 +
                                   hd * 16 + hi2 * 8];
#pragma unroll
  for (int qt = 0; qt < 2; ++qt)
    qf[qt] = *(const bf16x8*)&base[(long)WPIX(32 * qt + l31) * 768 +
                                   hd * 16 + hi2 * 8];

  bf16x8 vf[2];
#pragma unroll
  for (int kc = 0; kc < 2; ++kc)
#pragma unroll
    for (int j = 0; j < 8; ++j)
      vf[kc][j] = base[(long)WPIX(32 * kc + 8 * hi4 + j) * 768 + 512 +
                       hd * 16 + l15];

  f32x16 S[2][2];
#pragma unroll
  for (int kt = 0; kt < 2; ++kt)
#pragma unroll
    for (int qt = 0; qt < 2; ++qt)
#pragma unroll
      for (int r = 0; r < 16; ++r) S[kt][qt][r] = 0.f;

#pragma unroll
  for (int kt = 0; kt < 2; ++kt)
#pragma unroll
    for (int qt = 0; qt < 2; ++qt)
      S[kt][qt] = __builtin_amdgcn_mfma_f32_32x32x16_bf16(
          kf[kt], qf[qt], S[kt][qt], 0, 0, 0);

  __syncthreads();

  float mx[2] = {-1e30f, -1e30f};
#pragma unroll
  for (int kt = 0; kt < 2; ++kt)
#pragma unroll
    for (int r = 0; r < 16; ++r) {
      const int key = 32 * kt + (r & 3) + 8 * (r >> 2) + 4 * hi2;
      const int ky = key >> 3, kx = key & 7;
#pragma unroll
      for (int qt = 0; qt < 2; ++qt) {
        const int q = 32 * qt + l31;
        const int qy = q >> 3, qx = q & 7;
        float s = S[kt][qt][r] * 0.25f + srpb[(qy - ky + 7) * 15 + (qx - kx + 7)];
        S[kt][qt][r] = s;
        mx[qt] = fmaxf(mx[qt], s);
      }
    }
#pragma unroll
  for (int qt = 0; qt < 2; ++qt)
    mx[qt] = fmaxf(mx[qt], __shfl_xor(mx[qt], 32));

  float sum[2] = {0.f, 0.f};
#pragma unroll
  for (int kt = 0; kt < 2; ++kt)
#pragma unroll
    for (int qt = 0; qt < 2; ++qt)
#pragma unroll
      for (int r = 0; r < 16; ++r) {
        float e = __expf(S[kt][qt][r] - mx[qt]);
        S[kt][qt][r] = e;
        sum[qt] += e;
      }
#pragma unroll
  for (int qt = 0; qt < 2; ++qt) sum[qt] += __shfl_xor(sum[qt], 32);
  const float inv0 = 1.f / sum[0], inv1 = 1.f / sum[1];

#pragma unroll
  for (int qt = 0; qt < 2; ++qt) {
    const float inv = qt ? inv1 : inv0;
#pragma unroll
    for (int kt = 0; kt < 2; ++kt)
#pragma unroll
      for (int rq = 0; rq < 4; ++rq) {
        bf16x4 pk;
#pragma unroll
        for (int j = 0; j < 4; ++j) pk[j] = f2bf16(S[kt][qt][rq * 4 + j] * inv);
        *(bf16x4*)&P[32 * qt + l31][32 * kt + 8 * rq + 4 * hi2] = pk;
      }
  }
  __syncthreads();

  f32x4 o[4];
#pragma unroll
  for (int qt4 = 0; qt4 < 4; ++qt4) o[qt4] = (f32x4){0.f, 0.f, 0.f, 0.f};
#pragma unroll
  for (int kc = 0; kc < 2; ++kc)
#pragma unroll
    for (int qt4 = 0; qt4 < 4; ++qt4) {
      bf16x8 pf = *(const bf16x8*)&P[16 * qt4 + l15][32 * kc + 8 * hi4];
      o[qt4] = __builtin_amdgcn_mfma_f32_16x16x32_bf16(vf[kc], pf, o[qt4], 0, 0, 0);
    }

#pragma unroll
  for (int qt4 = 0; qt4 < 4; ++qt4)
#pragma unroll
    for (int r = 0; r < 4; ++r) {
      const int q = 16 * qt4 + l15;
      attnO[((long)b * C + hd * 16 + 4 * hi4 + r) * NP + WPIX(q)] = o[qt4][r];
    }
#undef WPIX
}

// ---------------- fused pools + combine + depthwise conv + BN --------------
__global__ __launch_bounds__(256) void pool_dw(
    const float* __restrict__ attn, const float* __restrict__ localO,
    const float* __restrict__ dww,
    const float* __restrict__ bnp_g, const float* __restrict__ bnp_b,
    const float* __restrict__ bnp_m, const float* __restrict__ bnp_v,
    float* __restrict__ dst)
{
  const int cb = blockIdx.x;
  const int c = cb & 255, b = cb >> 8;
  __shared__ float img[96 * 97];
  __shared__ float img2[96 * 97];
  const int t = threadIdx.x;
  const float* A = attn + ((long)b * C + c) * NP;
#pragma unroll
  for (int i = 0; i < 9; ++i) {
    int idx = i * 256 + t;
    float4 v = ((const float4*)A)[idx];
    float* d = &img[(idx / 24) * 97 + (idx % 24) * 4];
    d[0] = v.x; d[1] = v.y; d[2] = v.z; d[3] = v.w;
  }
  float wr[64];
#pragma unroll
  for (int i = 0; i < 64; ++i) wr[i] = dww[c * 64 + i];
  __syncthreads();

  const float* L = localO + ((long)b * C + c) * NP;
  for (int p = t; p < NP; p += 256) {
    const int h = p / 96, w = p % 96;
    float mph = -1e30f, aph = 0.f, mpw = -1e30f, apw = 0.f;
#pragma unroll
    for (int i = 0; i < 8; ++i) {
      int r = h - 3 + i;
      if (r >= 0 && r <= 96) {
        int rr = (r == 96) ? 94 : r;
        float v = img[rr * 97 + w];
        mph = fmaxf(mph, v); aph += v;
      }
      int s = w - 3 + i;
      if (s >= 0 && s <= 96) {
        int ss = (s == 96) ? 94 : s;
        float v = img[h * 97 + ss];
        mpw = fmaxf(mpw, v); apw += v;
      }
    }
    img2[h * 97 + w] = mph + mpw + (aph + apw) * 0.125f + L[p];
  }
  __syncthreads();

  const float sc  = bnp_g[c] * rsqrtf(bnp_v[c] + 1e-5f);
  const float off = bnp_b[c] - bnp_m[c] * sc;

  for (int seg = t; seg < 1152; seg += 256) {
    const int h = seg / 12, w0 = (seg % 12) * 8;
    float acc[8] = {0, 0, 0, 0, 0, 0, 0, 0};
#pragma unroll
    for (int i = 0; i < 8; ++i) {
      int r = h + i - 3;
      if (r < 0 || r > 96) continue;
      int rr = (r == 96) ? 94 : r;
      float win[15];
#pragma unroll
      for (int jj = 0; jj < 15; ++jj) {
        int cc = w0 + jj - 3;
        win[jj] = (cc >= 0 && cc <= 96) ? img2[rr * 97 + ((cc == 96) ? 94 : cc)]
                                        : 0.f;
      }
#pragma unroll
      for (int j = 0; j < 8; ++j)
#pragma unroll
        for (int jj = 0; jj < 8; ++jj)
          acc[j] = fmaf(wr[i * 8 + jj], win[j + jj], acc[j]);
    }
    const long o = ((long)b * C + c) * NP + h * 96 + w0;
#pragma unroll
    for (int j = 0; j < 8; ++j) dst[o + j] = acc[j] * sc + off;
  }
}

// ---------------- bf16-W x fp32-X GEMM (channel-major out) — pw only -------
__global__ __launch_bounds__(256) void gemm_xf32(
    const unsigned short* __restrict__ W, const float* __restrict__ X,
    float* __restrict__ Co, long xStride, long cStride)
{
  __shared__ unsigned short As[128][40];
  __shared__ unsigned short Bs[128][40];

  const int t = threadIdx.x;
  const int lane = t & 63, wid = t >> 6;
  const int wm = wid >> 1, wn = wid & 1;
  const int l15 = lane & 15, l4 = lane >> 4;
  const int n0 = blockIdx.x * 128, m0 = blockIdx.y * 128;
  const float* Xb = X + (long)blockIdx.z * xStride;
  float* Cb = Co + (long)blockIdx.z * cStride;

  f32x4 acc[4][4];
#pragma unroll
  for (int i = 0; i < 4; ++i)
#pragma unroll
    for (int j = 0; j < 4; ++j) acc[i][j] = (f32x4){0.f, 0.f, 0.f, 0.f};

  for (int k0 = 0; k0 < 256; k0 += 32) {
#pragma unroll
    for (int i = 0; i < 2; ++i) {
      int s = i * 256 + t, m = s >> 2, kq = s & 3;
      *(uint4*)&As[m][kq * 8] =
          *(const uint4*)&W[(long)(m0 + m) * 256 + k0 + kq * 8];
    }
#pragma unroll
    for (int i = 0; i < 4; ++i) {
      int s = i * 256 + t, kk = s >> 5, nq = s & 31;
      float4 v = *(const float4*)&Xb[(long)(k0 + kk) * NP + n0 + nq * 4];
      Bs[nq * 4 + 0][kk] = f2bf_rne(v.x);
      Bs[nq * 4 + 1][kk] = f2bf_rne(v.y);
      Bs[nq * 4 + 2][kk] = f2bf_rne(v.z);
      Bs[nq * 4 + 3][kk] = f2bf_rne(v.w);
    }
    __syncthreads();

    bf16x8 af[4], bb[4];
#pragma unroll
    for (int mf = 0; mf < 4; ++mf)
      af[mf] = *(const bf16x8*)&As[wm * 64 + mf * 16 + l15][l4 * 8];
#pragma unroll
    for (int nf = 0; nf < 4; ++nf)
      bb[nf] = *(const bf16x8*)&Bs[wn * 64 + nf * 16 + l15][l4 * 8];
#pragma unroll
    for (int mf = 0; mf < 4; ++mf)
#pragma unroll
      for (int nf = 0; nf < 4; ++nf)
        acc[mf][nf] = __builtin_amdgcn_mfma_f32_16x16x32_bf16(
            af[mf], bb[nf], acc[mf][nf], 0, 0, 0);
    __syncthreads();
  }

#pragma unroll
  for (int mf = 0; mf < 4; ++mf)
#pragma unroll
    for (int r = 0; r < 4; ++r) {
      int row = m0 + wm * 64 + mf * 16 + l4 * 4 + r;
#pragma unroll
      for (int nf = 0; nf < 4; ++nf) {
        int col = n0 + wn * 64 + nf * 16 + l15;
        Cb[(long)row * NP + col] = acc[mf][nf][r];
      }
    }
}

}  // namespace

extern "C" void kernel_launch(void* const* d_in, const int* in_sizes, int n_in,
                              void* d_out, int out_size, void* d_ws, size_t ws_size,
                              hipStream_t stream) {
  const float* x         = (const float*)d_in[0];
  const float* qkv_w     = (const float*)d_in[1];
  const float* l2_w      = (const float*)d_in[2];
  const float* bn2_g     = (const float*)d_in[3];
  const float* bn2_b     = (const float*)d_in[4];
  const float* bn2_m     = (const float*)d_in[5];
  const float* bn2_v     = (const float*)d_in[6];
  const float* wq        = (const float*)d_in[7];
  const float* wk        = (const float*)d_in[8];
  const float* wv        = (const float*)d_in[9];
  const float* rel_x     = (const float*)d_in[10];
  const float* rel_y     = (const float*)d_in[11];
  const float* l1_bias   = (const float*)d_in[12];
  const float* rel_table = (const float*)d_in[13];
  const float* dw_w      = (const float*)d_in[14];
  const float* bnp_g     = (const float*)d_in[15];
  const float* bnp_b     = (const float*)d_in[16];
  const float* bnp_m     = (const float*)d_in[17];
  const float* bnp_v     = (const float*)d_in[18];
  const float* pw_w      = (const float*)d_in[19];
  float* out = (float*)d_out;
  float* ws  = (float*)d_ws;

  unsigned short* GA     = (unsigned short*)ws;
  unsigned short* GB     = (unsigned short*)ws;
  float*          dwB    = ws;
  float*          localB = ws + 9437184;
  float*          attnB  = ws + 14155776;
  unsigned short* W7     = (unsigned short*)(ws + 20971520);
  unsigned short* XT     = (unsigned short*)(ws + 21233664);

  // 1. x -> XT bf16 [pix][256]
  xpose<<<dim3(144, 4, 2), 256, 0, stream>>>(x, XT);

  // 2. all weights -> W7 bf16
  cvt_w7<<<dim3(2048), 256, 0, stream>>>(l2_w, wq, wk, wv, qkv_w, pw_w, W7);

  // 3. [l2|qL|kL|vL] -> GA bf16 [pix][1024]
  gemm_bt<<<dim3(72, 8, 2), 256, 0, stream>>>(W7, XT, GA, 1024);

  // 4. neighborhood attention + BN + bias -> localB
  local_attn2<<<dim3(288, 2), 256, 0, stream>>>(GA, rel_x, rel_y, bn2_g, bn2_b,
                                                bn2_m, bn2_v, l1_bias, localB);

  // 5. qkv -> GB bf16 [pix][768] (over GA)
  gemm_bt<<<dim3(72, 6, 2), 256, 0, stream>>>(W7 + 1024 * 256, XT, GB, 768);

  // 6. window attention (MFMA) -> attnB
  window_attn_mfma<<<dim3(144, 16, 2), 64, 0, stream>>>(GB, rel_table, attnB);

  // 7. pools + combine + depthwise conv + BN -> dwB
  pool_dw<<<dim3(512), 256, 0, stream>>>(attnB, localB, dw_w, bnp_g, bnp_b,
                                         bnp_m, bnp_v, dwB);

  // 8. pointwise GEMM -> out
  gemm_xf32<<<dim3(72, 2, 2), 256, 0, stream>>>(W7 + 1792 * 256, dwB, out,
                                                (long)C * NP, (long)C * NP);
}

// Round 5
// 190.809 us; speedup vs baseline: 3.0310x; 1.0744x over previous
//
#include <hip/hip_runtime.h>
#include <math.h>

// GlobalLocalAttention — round 4: tiled pool_dw + conflict-free final GEMM.
//
// Pipeline:
//  1. xpose:   x fp32 [b][256][NP] -> XT bf16 [b][NP][256]
//  2. cvt_w7:  all weights -> W7 bf16 [2048][256]
//  3. gemm_bt(W7[0:1024])    -> GA bf16 [b][NP][1024]
//  4. local_attn2(GA)        -> localB fp32 [b][256][NP]
//  5. gemm_bt(W7[1024:1792]) -> GB bf16 [b][NP][768]   (over GA, dead)
//  6. window_attn_mfma(GB)   -> attnB fp32 [b][256][NP]
//  7. pool_dw2 (pool+combine+dwconv+BN, row-tiled) -> dwB fp32 [b][256][NP]
//  8. xpose(dwB)             -> XT2 bf16 [b][NP][256]
//  9. gemm_cf32(W7[1792:2048], XT2) -> d_out fp32 [b][256][NP]
//
// Workspace layout (floats, 23,592,960 total):
//  GA/GB [0 ..)            dwB [0 .. 4,718,592)
//  XT2   [4,718,592 .. 7,077,888)
//  localB [9,437,184 .. 14,155,776)
//  attnB  [14,155,776 .. 18,874,368)
//  W7     [20,971,520 .. 21,233,664)
//  XT     [21,233,664 .. 23,592,960)

namespace {

constexpr int NP = 96 * 96;   // 9216
constexpr int C  = 256;

typedef __bf16 bf16x8 __attribute__((ext_vector_type(8)));
typedef float  f32x4  __attribute__((ext_vector_type(4)));
typedef float  f32x16 __attribute__((ext_vector_type(16)));
typedef __bf16 bf16x4 __attribute__((ext_vector_type(4)));

__device__ __forceinline__ unsigned short f2bf_rne(float f) {
  unsigned u = __float_as_uint(f);
  u += 0x7FFFu + ((u >> 16) & 1u);
  return (unsigned short)(u >> 16);
}
__device__ __forceinline__ __bf16 f2bf16(float f) {
  unsigned short s = f2bf_rne(f);
  return *(__bf16*)&s;
}

// ---------------- transpose: fp32 [c][pix] -> bf16 [pix][c] ----------------
__global__ __launch_bounds__(256) void xpose(
    const float* __restrict__ x, unsigned short* __restrict__ XT)
{
  __shared__ float tile[64][65];
  const int t = threadIdx.x;
  const int p0 = blockIdx.x * 64, c0 = blockIdx.y * 64, b = blockIdx.z;
  const float* xb = x + (long)b * C * NP;
#pragma unroll
  for (int i = 0; i < 4; ++i) {
    int s = i * 256 + t;                 // 0..1023
    int c = s >> 4, p4 = s & 15;
    float4 v = *(const float4*)&xb[(long)(c0 + c) * NP + p0 + p4 * 4];
    tile[c][p4 * 4 + 0] = v.x;
    tile[c][p4 * 4 + 1] = v.y;
    tile[c][p4 * 4 + 2] = v.z;
    tile[c][p4 * 4 + 3] = v.w;
  }
  __syncthreads();
  unsigned short* XTb = XT + (long)b * NP * 256;
#pragma unroll
  for (int i = 0; i < 2; ++i) {
    int s = i * 256 + t;                 // 0..511
    int p = s >> 3, c8 = s & 7;
    unsigned short u[8];
#pragma unroll
    for (int e = 0; e < 8; ++e) u[e] = f2bf_rne(tile[c8 * 8 + e][p]);
    *(uint4*)&XTb[(long)(p0 + p) * 256 + c0 + c8 * 8] = *(const uint4*)u;
  }
}

// ---------------- all weights -> bf16 (one row per block) ------------------
__global__ __launch_bounds__(256) void cvt_w7(
    const float* __restrict__ l2, const float* __restrict__ q,
    const float* __restrict__ k,  const float* __restrict__ v,
    const float* __restrict__ qkv, const float* __restrict__ pw,
    unsigned short* __restrict__ W7)
{
  const int row = blockIdx.x;            // 0..2047
  const float* src; int r;
  if      (row <  256) { src = l2;  r = row; }
  else if (row <  512) { src = q;   r = row - 256; }
  else if (row <  768) { src = k;   r = row - 512; }
  else if (row < 1024) { src = v;   r = row - 768; }
  else if (row < 1792) { src = qkv; r = row - 1024; }
  else                 { src = pw;  r = row - 1792; }
  W7[row * 256 + threadIdx.x] = f2bf_rne(src[r * 256 + threadIdx.x]);
}

// ---------------- bf16 GEMM: W[M][256] x XT[pix][256]^T -> O[pix][M] bf16 --
__global__ __launch_bounds__(256) void gemm_bt(
    const unsigned short* __restrict__ W, const unsigned short* __restrict__ XT,
    unsigned short* __restrict__ O, int Mstride)
{
  __shared__ __align__(16) char smem[36864];
  unsigned short (*As)[40] = reinterpret_cast<unsigned short(*)[40]>(smem);
  unsigned short (*Bs)[40] = reinterpret_cast<unsigned short(*)[40]>(smem + 10240);

  const int t = threadIdx.x;
  const int lane = t & 63, wid = t >> 6;
  const int wm = wid >> 1, wn = wid & 1;
  const int l15 = lane & 15, l4 = lane >> 4;
  const int n0 = blockIdx.x * 128, m0 = blockIdx.y * 128;
  const unsigned short* XTb = XT + (long)blockIdx.z * NP * 256;
  unsigned short* Ob = O + (long)blockIdx.z * NP * Mstride;

  f32x4 acc[4][4];
#pragma unroll
  for (int i = 0; i < 4; ++i)
#pragma unroll
    for (int j = 0; j < 4; ++j) acc[i][j] = (f32x4){0.f, 0.f, 0.f, 0.f};

  for (int k0 = 0; k0 < 256; k0 += 32) {
#pragma unroll
    for (int i = 0; i < 2; ++i) {
      int s = i * 256 + t, r = s >> 2, kc = s & 3;
      *(uint4*)&As[r][kc * 8] =
          *(const uint4*)&W[(long)(m0 + r) * 256 + k0 + kc * 8];
    }
#pragma unroll
    for (int i = 0; i < 2; ++i) {
      int s = i * 256 + t, r = s >> 2, kc = s & 3;
      *(uint4*)&Bs[r][kc * 8] =
          *(const uint4*)&XTb[(long)(n0 + r) * 256 + k0 + kc * 8];
    }
    __syncthreads();

    bf16x8 af[4], bb[4];
#pragma unroll
    for (int mf = 0; mf < 4; ++mf)
      af[mf] = *(const bf16x8*)&As[wm * 64 + mf * 16 + l15][l4 * 8];
#pragma unroll
    for (int nf = 0; nf < 4; ++nf)
      bb[nf] = *(const bf16x8*)&Bs[wn * 64 + nf * 16 + l15][l4 * 8];
#pragma unroll
    for (int mf = 0; mf < 4; ++mf)
#pragma unroll
      for (int nf = 0; nf < 4; ++nf)
        acc[mf][nf] = __builtin_amdgcn_mfma_f32_16x16x32_bf16(
            af[mf], bb[nf], acc[mf][nf], 0, 0, 0);
    __syncthreads();
  }

  // epilogue: per-wave 64pix x 64chan transpose via LDS (aliased over As/Bs)
  unsigned short* trw = (unsigned short*)smem + wid * 64 * 72;
#pragma unroll
  for (int mf = 0; mf < 4; ++mf)
#pragma unroll
    for (int nf = 0; nf < 4; ++nf) {
      unsigned u0 = (unsigned)f2bf_rne(acc[mf][nf][0]) |
                    ((unsigned)f2bf_rne(acc[mf][nf][1]) << 16);
      unsigned u1 = (unsigned)f2bf_rne(acc[mf][nf][2]) |
                    ((unsigned)f2bf_rne(acc[mf][nf][3]) << 16);
      uint2 uu; uu.x = u0; uu.y = u1;
      *(uint2*)&trw[(nf * 16 + l15) * 72 + mf * 16 + l4 * 4] = uu;
    }
  __syncthreads();

  const long pix = n0 + wn * 64 + lane;
  const long rowbase = pix * Mstride + m0 + wm * 64;
#pragma unroll
  for (int cc = 0; cc < 8; ++cc)
    *(uint4*)&Ob[rowbase + cc * 8] = *(const uint4*)&trw[lane * 72 + cc * 8];
}

// ---------------- bf16 GEMM, fp32 channel-major output (final pw) ----------
__global__ __launch_bounds__(256) void gemm_cf32(
    const unsigned short* __restrict__ W, const unsigned short* __restrict__ XT,
    float* __restrict__ Co)
{
  __shared__ unsigned short As[128][40];
  __shared__ unsigned short Bs[128][40];

  const int t = threadIdx.x;
  const int lane = t & 63, wid = t >> 6;
  const int wm = wid >> 1, wn = wid & 1;
  const int l15 = lane & 15, l4 = lane >> 4;
  const int n0 = blockIdx.x * 128, m0 = blockIdx.y * 128;
  const unsigned short* XTb = XT + (long)blockIdx.z * NP * 256;
  float* Cb = Co + (long)blockIdx.z * C * NP;

  f32x4 acc[4][4];
#pragma unroll
  for (int i = 0; i < 4; ++i)
#pragma unroll
    for (int j = 0; j < 4; ++j) acc[i][j] = (f32x4){0.f, 0.f, 0.f, 0.f};

  for (int k0 = 0; k0 < 256; k0 += 32) {
#pragma unroll
    for (int i = 0; i < 2; ++i) {
      int s = i * 256 + t, r = s >> 2, kc = s & 3;
      *(uint4*)&As[r][kc * 8] =
          *(const uint4*)&W[(long)(m0 + r) * 256 + k0 + kc * 8];
    }
#pragma unroll
    for (int i = 0; i < 2; ++i) {
      int s = i * 256 + t, r = s >> 2, kc = s & 3;
      *(uint4*)&Bs[r][kc * 8] =
          *(const uint4*)&XTb[(long)(n0 + r) * 256 + k0 + kc * 8];
    }
    __syncthreads();

    bf16x8 af[4], bb[4];
#pragma unroll
    for (int mf = 0; mf < 4; ++mf)
      af[mf] = *(const bf16x8*)&As[wm * 64 + mf * 16 + l15][l4 * 8];
#pragma unroll
    for (int nf = 0; nf < 4; ++nf)
      bb[nf] = *(const bf16x8*)&Bs[wn * 64 + nf * 16 + l15][l4 * 8];
#pragma unroll
    for (int mf = 0; mf < 4; ++mf)
#pragma unroll
      for (int nf = 0; nf < 4; ++nf)
        acc[mf][nf] = __builtin_amdgcn_mfma_f32_16x16x32_bf16(
            af[mf], bb[nf], acc[mf][nf], 0, 0, 0);
    __syncthreads();
  }

#pragma unroll
  for (int mf = 0; mf < 4; ++mf)
#pragma unroll
    for (int r = 0; r < 4; ++r) {
      int row = m0 + wm * 64 + mf * 16 + l4 * 4 + r;
#pragma unroll
      for (int nf = 0; nf < 4; ++nf) {
        int col = n0 + wn * 64 + nf * 16 + l15;
        Cb[(long)row * NP + col] = acc[mf][nf][r];
      }
    }
}

// ---------------- 3x3 neighborhood attention + BN + bias (pixel-major) -----
__global__ __launch_bounds__(256) void local_attn2(
    const unsigned short* __restrict__ GA,
    const float* __restrict__ rel_x, const float* __restrict__ rel_y,
    const float* __restrict__ bn2_g, const float* __restrict__ bn2_b,
    const float* __restrict__ bn2_m, const float* __restrict__ bn2_v,
    const float* __restrict__ l1_bias, float* __restrict__ localO)
{
  const int b = blockIdx.y, t = threadIdx.x;
  const int px = t & 31, ch = t >> 5;          // ch 0..7
  const int p = blockIdx.x * 32 + px;
  const unsigned short* Gb = GA + (long)b * NP * 1024;

  __shared__ float red[8][32][13];
  __shared__ float srel[256 * 3];
  __shared__ float sS[256], sO[256], sBias[256];

  if (t < 128) {
    srel[t * 3 + 0] = rel_x[t * 3 + 0];
    srel[t * 3 + 1] = rel_x[t * 3 + 1];
    srel[t * 3 + 2] = rel_x[t * 3 + 2];
  } else {
    int r = t - 128;
    srel[t * 3 + 0] = rel_y[r * 3 + 0];
    srel[t * 3 + 1] = rel_y[r * 3 + 1];
    srel[t * 3 + 2] = rel_y[r * 3 + 2];
  }
  {
    float s = bn2_g[t] * rsqrtf(bn2_v[t] + 1e-5f);
    sS[t] = s;
    sO[t] = bn2_b[t] - bn2_m[t] * s;
    sBias[t] = l1_bias[t];
  }

  const int h = p / 96, w = p % 96;
  int nof[9];
  float msk[9];
#pragma unroll
  for (int ky = 0; ky < 3; ++ky)
#pragma unroll
    for (int kx = 0; kx < 3; ++kx) {
      int j = ky * 3 + kx, hn = h + ky - 1, wn = w + kx - 1;
      bool v = (hn >= 0 && hn < 96 && wn >= 0 && wn < 96);
      nof[j] = v ? hn * 96 + wn : p;
      msk[j] = v ? 1.f : 0.f;
    }
  __syncthreads();

  float lg[9] = {0, 0, 0, 0, 0, 0, 0, 0, 0};
  float rq[3] = {0, 0, 0};
  const int c0 = ch * 32;
#pragma unroll
  for (int i = 0; i < 4; ++i) {
    const int c = c0 + i * 8;
    bf16x8 q8 = *(const bf16x8*)&Gb[(long)p * 1024 + 256 + c];
    float qv[8];
#pragma unroll
    for (int e = 0; e < 8; ++e) qv[e] = (float)q8[e];
#pragma unroll
    for (int j = 0; j < 9; ++j) {
      bf16x8 k8 = *(const bf16x8*)&Gb[(long)nof[j] * 1024 + 512 + c];
#pragma unroll
      for (int e = 0; e < 8; ++e) lg[j] += qv[e] * (float)k8[e];
    }
#pragma unroll
    for (int e = 0; e < 8; ++e) {
      const float* sr = &srel[(c + e) * 3];
      rq[0] += qv[e] * sr[0];
      rq[1] += qv[e] * sr[1];
      rq[2] += qv[e] * sr[2];
    }
  }
#pragma unroll
  for (int j = 0; j < 9; ++j) red[ch][px][j] = lg[j] * msk[j];
#pragma unroll
  for (int l = 0; l < 3; ++l) red[ch][px][9 + l] = rq[l];
  __syncthreads();

  float a[9];
  float mx = -1e30f;
#pragma unroll
  for (int j = 0; j < 9; ++j) {
    float v = 0.f;
#pragma unroll
    for (int u = 0; u < 8; ++u) v += red[u][px][j];
    float qxl = red[0][px][9 + j % 3] + red[1][px][9 + j % 3] +
                red[2][px][9 + j % 3] + red[3][px][9 + j % 3];
    float qyk = red[4][px][9 + j / 3] + red[5][px][9 + j / 3] +
                red[6][px][9 + j / 3] + red[7][px][9 + j / 3];
    a[j] = v + qxl + qyk;
    mx = fmaxf(mx, a[j]);
  }
  float sum = 0.f;
#pragma unroll
  for (int j = 0; j < 9; ++j) { a[j] = __expf(a[j] - mx); sum += a[j]; }
  const float inv = 1.f / sum;
  float am[9];
#pragma unroll
  for (int j = 0; j < 9; ++j) am[j] = a[j] * inv * msk[j];

#pragma unroll
  for (int i = 0; i < 4; ++i) {
    const int c = c0 + i * 8;
    bf16x8 l28 = *(const bf16x8*)&Gb[(long)p * 1024 + 0 + c];
    float o8[8] = {0, 0, 0, 0, 0, 0, 0, 0};
#pragma unroll
    for (int j = 0; j < 9; ++j) {
      bf16x8 v8 = *(const bf16x8*)&Gb[(long)nof[j] * 1024 + 768 + c];
#pragma unroll
      for (int e = 0; e < 8; ++e) o8[e] += am[j] * (float)v8[e];
    }
#pragma unroll
    for (int e = 0; e < 8; ++e) {
      const int cg = c + e;
      localO[((long)b * C + cg) * NP + p] =
          (float)l28[e] * sS[cg] + sO[cg] + o8[e] + sBias[cg];
    }
  }
}

// ---------------- 8x8 window attention via MFMA (GB [pix][768]) ------------
__global__ __launch_bounds__(64) void window_attn_mfma(
    const unsigned short* __restrict__ QKV,
    const float* __restrict__ rel_table, float* __restrict__ attnO)
{
  const int win = blockIdx.x, hd = blockIdx.y, b = blockIdx.z;
  const int wy = win / 12, wx = win % 12;
  const int lane = threadIdx.x;
  const int l15 = lane & 15, hi4 = lane >> 4;
  const int l31 = lane & 31, hi2 = lane >> 5;

  __shared__ float srpb[225];
  __shared__ __bf16 P[64][72];

  for (int i = lane; i < 225; i += 64) srpb[i] = rel_table[i * 16 + hd];

  const __bf16* base = (const __bf16*)QKV + (long)b * 9216 * 768;
  const int pixbase = (wy * 8) * 96 + wx * 8;

#define WPIX(i) (pixbase + ((i) >> 3) * 96 + ((i) & 7))

  bf16x8 kf[2], qf[2];
#pragma unroll
  for (int kt = 0; kt < 2; ++kt)
    kf[kt] = *(const bf16x8*)&base[(long)WPIX(32 * kt + l31) * 768 + 256 +
                                   hd * 16 + hi2 * 8];
#pragma unroll
  for (int qt = 0; qt < 2; ++qt)
    qf[qt] = *(const bf16x8*)&base[(long)WPIX(32 * qt + l31) * 768 +
                                   hd * 16 + hi2 * 8];

  bf16x8 vf[2];
#pragma unroll
  for (int kc = 0; kc < 2; ++kc)
#pragma unroll
    for (int j = 0; j < 8; ++j)
      vf[kc][j] = base[(long)WPIX(32 * kc + 8 * hi4 + j) * 768 + 512 +
                       hd * 16 + l15];

  f32x16 S[2][2];
#pragma unroll
  for (int kt = 0; kt < 2; ++kt)
#pragma unroll
    for (int qt = 0; qt < 2; ++qt)
#pragma unroll
      for (int r = 0; r < 16; ++r) S[kt][qt][r] = 0.f;

#pragma unroll
  for (int kt = 0; kt < 2; ++kt)
#pragma unroll
    for (int qt = 0; qt < 2; ++qt)
      S[kt][qt] = __builtin_amdgcn_mfma_f32_32x32x16_bf16(
          kf[kt], qf[qt], S[kt][qt], 0, 0, 0);

  __syncthreads();

  float mx[2] = {-1e30f, -1e30f};
#pragma unroll
  for (int kt = 0; kt < 2; ++kt)
#pragma unroll
    for (int r = 0; r < 16; ++r) {
      const int key = 32 * kt + (r & 3) + 8 * (r >> 2) + 4 * hi2;
      const int ky = key >> 3, kx = key & 7;
#pragma unroll
      for (int qt = 0; qt < 2; ++qt) {
        const int q = 32 * qt + l31;
        const int qy = q >> 3, qx = q & 7;
        float s = S[kt][qt][r] * 0.25f + srpb[(qy - ky + 7) * 15 + (qx - kx + 7)];
        S[kt][qt][r] = s;
        mx[qt] = fmaxf(mx[qt], s);
      }
    }
#pragma unroll
  for (int qt = 0; qt < 2; ++qt)
    mx[qt] = fmaxf(mx[qt], __shfl_xor(mx[qt], 32));

  float sum[2] = {0.f, 0.f};
#pragma unroll
  for (int kt = 0; kt < 2; ++kt)
#pragma unroll
    for (int qt = 0; qt < 2; ++qt)
#pragma unroll
      for (int r = 0; r < 16; ++r) {
        float e = __expf(S[kt][qt][r] - mx[qt]);
        S[kt][qt][r] = e;
        sum[qt] += e;
      }
#pragma unroll
  for (int qt = 0; qt < 2; ++qt) sum[qt] += __shfl_xor(sum[qt], 32);
  const float inv0 = 1.f / sum[0], inv1 = 1.f / sum[1];

#pragma unroll
  for (int qt = 0; qt < 2; ++qt) {
    const float inv = qt ? inv1 : inv0;
#pragma unroll
    for (int kt = 0; kt < 2; ++kt)
#pragma unroll
      for (int rq = 0; rq < 4; ++rq) {
        bf16x4 pk;
#pragma unroll
        for (int j = 0; j < 4; ++j) pk[j] = f2bf16(S[kt][qt][rq * 4 + j] * inv);
        *(bf16x4*)&P[32 * qt + l31][32 * kt + 8 * rq + 4 * hi2] = pk;
      }
  }
  __syncthreads();

  f32x4 o[4];
#pragma unroll
  for (int qt4 = 0; qt4 < 4; ++qt4) o[qt4] = (f32x4){0.f, 0.f, 0.f, 0.f};
#pragma unroll
  for (int kc = 0; kc < 2; ++kc)
#pragma unroll
    for (int qt4 = 0; qt4 < 4; ++qt4) {
      bf16x8 pf = *(const bf16x8*)&P[16 * qt4 + l15][32 * kc + 8 * hi4];
      o[qt4] = __builtin_amdgcn_mfma_f32_16x16x32_bf16(vf[kc], pf, o[qt4], 0, 0, 0);
    }

#pragma unroll
  for (int qt4 = 0; qt4 < 4; ++qt4)
#pragma unroll
    for (int r = 0; r < 4; ++r) {
      const int q = 16 * qt4 + l15;
      attnO[((long)b * C + hd * 16 + 4 * hi4 + r) * NP + WPIX(q)] = o[qt4][r];
    }
#undef WPIX
}

// ---------------- fused pools + combine + dw conv + BN (row-tiled) ---------
// 4 row-tiles of 24 output rows per (b,c).  LDS: img 38x97 + img2 31x97.
__global__ __launch_bounds__(256) void pool_dw2(
    const float* __restrict__ attn, const float* __restrict__ localO,
    const float* __restrict__ dww,
    const float* __restrict__ bnp_g, const float* __restrict__ bnp_b,
    const float* __restrict__ bnp_m, const float* __restrict__ bnp_v,
    float* __restrict__ dst)
{
  const int tile = blockIdx.x;           // 0..3
  const int c = blockIdx.y, b = blockIdx.z;
  const int r0 = tile * 24;
  const int r2lo = max(0, r0 - 3), r2hi = min(95, r0 + 27);
  const int rlo = max(0, r2lo - 3), rhi = min(95, r2hi + 4);
  const int nr = rhi - rlo + 1;          // <= 38
  const int n2 = r2hi - r2lo + 1;        // <= 31

  __shared__ float img[38 * 97];
  __shared__ float img2[31 * 97];
  const int t = threadIdx.x;
  const float* A = attn + ((long)b * C + c) * NP;

  for (int idx = t; idx < nr * 24; idx += 256) {
    int r = idx / 24, q = idx % 24;
    float4 v = *(const float4*)&A[(rlo + r) * 96 + q * 4];
    float* d = &img[r * 97 + q * 4];
    d[0] = v.x; d[1] = v.y; d[2] = v.z; d[3] = v.w;
  }
  float wr[64];
#pragma unroll
  for (int i = 0; i < 64; ++i) wr[i] = dww[c * 64 + i];
  __syncthreads();

  // pools + combine with localO -> img2
  const float* L = localO + ((long)b * C + c) * NP;
  for (int idx = t; idx < n2 * 96; idx += 256) {
    int j = idx / 96, w = idx % 96;
    int gr = r2lo + j;
    float mph = -1e30f, aph = 0.f, mpw = -1e30f, apw = 0.f;
#pragma unroll
    for (int i = 0; i < 8; ++i) {
      int r = gr - 3 + i;
      if (r >= 0 && r <= 96) {
        int rr = (r == 96) ? 94 : r;
        float v = img[(rr - rlo) * 97 + w];
        mph = fmaxf(mph, v); aph += v;
      }
      int s = w - 3 + i;
      if (s >= 0 && s <= 96) {
        int ss = (s == 96) ? 94 : s;
        float v = img[(gr - rlo) * 97 + ss];
        mpw = fmaxf(mpw, v); apw += v;
      }
    }
    img2[j * 97 + w] = mph + mpw + (aph + apw) * 0.125f + L[gr * 96 + w];
  }
  __syncthreads();

  const float sc  = bnp_g[c] * rsqrtf(bnp_v[c] + 1e-5f);
  const float off = bnp_b[c] - bnp_m[c] * sc;

  // depthwise 8x8 conv over img2 (24 rows x 12 eight-wide segs)
  for (int seg = t; seg < 288; seg += 256) {
    const int hh = seg / 12, w0 = (seg % 12) * 8;
    const int h = r0 + hh;
    float acc[8] = {0, 0, 0, 0, 0, 0, 0, 0};
#pragma unroll
    for (int i = 0; i < 8; ++i) {
      int r = h + i - 3;
      if (r < 0 || r > 96) continue;
      int rr = (r == 96) ? 94 : r;
      const float* row = &img2[(rr - r2lo) * 97];
      float win[15];
#pragma unroll
      for (int jj = 0; jj < 15; ++jj) {
        int cc = w0 + jj - 3;
        win[jj] = (cc >= 0 && cc <= 96) ? row[(cc == 96) ? 94 : cc] : 0.f;
      }
#pragma unroll
      for (int j = 0; j < 8; ++j)
#pragma unroll
        for (int jj = 0; jj < 8; ++jj)
          acc[j] = fmaf(wr[i * 8 + jj], win[j + jj], acc[j]);
    }
    const long o = ((long)b * C + c) * NP + h * 96 + w0;
#pragma unroll
    for (int j = 0; j < 8; ++j) dst[o + j] = acc[j] * sc + off;
  }
}

}  // namespace

extern "C" void kernel_launch(void* const* d_in, const int* in_sizes, int n_in,
                              void* d_out, int out_size, void* d_ws, size_t ws_size,
                              hipStream_t stream) {
  const float* x         = (const float*)d_in[0];
  const float* qkv_w     = (const float*)d_in[1];
  const float* l2_w      = (const float*)d_in[2];
  const float* bn2_g     = (const float*)d_in[3];
  const float* bn2_b     = (const float*)d_in[4];
  const float* bn2_m     = (const float*)d_in[5];
  const float* bn2_v     = (const float*)d_in[6];
  const float* wq        = (const float*)d_in[7];
  const float* wk        = (const float*)d_in[8];
  const float* wv        = (const float*)d_in[9];
  const float* rel_x     = (const float*)d_in[10];
  const float* rel_y     = (const float*)d_in[11];
  const float* l1_bias   = (const float*)d_in[12];
  const float* rel_table = (const float*)d_in[13];
  const float* dw_w      = (const float*)d_in[14];
  const float* bnp_g     = (const float*)d_in[15];
  const float* bnp_b     = (const float*)d_in[16];
  const float* bnp_m     = (const float*)d_in[17];
  const float* bnp_v     = (const float*)d_in[18];
  const float* pw_w      = (const float*)d_in[19];
  float* out = (float*)d_out;
  float* ws  = (float*)d_ws;

  unsigned short* GA     = (unsigned short*)ws;
  unsigned short* GB     = (unsigned short*)ws;
  float*          dwB    = ws;
  unsigned short* XT2    = (unsigned short*)(ws + 4718592);
  float*          localB = ws + 9437184;
  float*          attnB  = ws + 14155776;
  unsigned short* W7     = (unsigned short*)(ws + 20971520);
  unsigned short* XT     = (unsigned short*)(ws + 21233664);

  // 1. x -> XT bf16 [pix][256]
  xpose<<<dim3(144, 4, 2), 256, 0, stream>>>(x, XT);

  // 2. all weights -> W7 bf16
  cvt_w7<<<dim3(2048), 256, 0, stream>>>(l2_w, wq, wk, wv, qkv_w, pw_w, W7);

  // 3. [l2|qL|kL|vL] -> GA bf16 [pix][1024]
  gemm_bt<<<dim3(72, 8, 2), 256, 0, stream>>>(W7, XT, GA, 1024);

  // 4. neighborhood attention + BN + bias -> localB
  local_attn2<<<dim3(288, 2), 256, 0, stream>>>(GA, rel_x, rel_y, bn2_g, bn2_b,
                                                bn2_m, bn2_v, l1_bias, localB);

  // 5. qkv -> GB bf16 [pix][768] (over GA)
  gemm_bt<<<dim3(72, 6, 2), 256, 0, stream>>>(W7 + 1024 * 256, XT, GB, 768);

  // 6. window attention (MFMA) -> attnB
  window_attn_mfma<<<dim3(144, 16, 2), 64, 0, stream>>>(GB, rel_table, attnB);

  // 7. pools + combine + depthwise conv + BN -> dwB (row-tiled)
  pool_dw2<<<dim3(4, 256, 2), 256, 0, stream>>>(attnB, localB, dw_w, bnp_g,
                                                bnp_b, bnp_m, bnp_v, dwB);

  // 8. dwB -> XT2 bf16 [pix][256]
  xpose<<<dim3(144, 4, 2), 256, 0, stream>>>(dwB, XT2);

  // 9. pointwise GEMM -> out (fp32 channel-major)
  gemm_cf32<<<dim3(72, 2, 2), 256, 0, stream>>>(W7 + 1792 * 256, XT2, out);
}

// Round 6
// 177.971 us; speedup vs baseline: 3.2496x; 1.0721x over previous
//
#include <hip/hip_runtime.h>
#include <math.h>

// GlobalLocalAttention — round 5: branch-free padded-LDS pool_dw3.
//
// Pipeline:
//  1. xpose:   x fp32 [b][256][NP] -> XT bf16 [b][NP][256]
//  2. cvt_w7:  all weights -> W7 bf16 [2048][256]
//  3. gemm_bt(W7[0:1024])    -> GA bf16 [b][NP][1024]
//  4. local_attn2(GA)        -> localB fp32 [b][256][NP]
//  5. gemm_bt(W7[1024:1792]) -> GB bf16 [b][NP][768]   (over GA, dead)
//  6. window_attn_mfma(GB)   -> attnB fp32 [b][256][NP]
//  7. pool_dw3 (pool+combine+dwconv+BN, padded-LDS) -> dwB fp32
//  8. xpose(dwB)             -> XT2 bf16 [b][NP][256]
//  9. gemm_cf32(W7[1792:2048], XT2) -> d_out fp32 [b][256][NP]

namespace {

constexpr int NP = 96 * 96;   // 9216
constexpr int C  = 256;

typedef __bf16 bf16x8 __attribute__((ext_vector_type(8)));
typedef float  f32x4  __attribute__((ext_vector_type(4)));
typedef float  f32x16 __attribute__((ext_vector_type(16)));
typedef __bf16 bf16x4 __attribute__((ext_vector_type(4)));

__device__ __forceinline__ unsigned short f2bf_rne(float f) {
  unsigned u = __float_as_uint(f);
  u += 0x7FFFu + ((u >> 16) & 1u);
  return (unsigned short)(u >> 16);
}
__device__ __forceinline__ __bf16 f2bf16(float f) {
  unsigned short s = f2bf_rne(f);
  return *(__bf16*)&s;
}

// ---------------- transpose: fp32 [c][pix] -> bf16 [pix][c] ----------------
__global__ __launch_bounds__(256) void xpose(
    const float* __restrict__ x, unsigned short* __restrict__ XT)
{
  __shared__ float tile[64][65];
  const int t = threadIdx.x;
  const int p0 = blockIdx.x * 64, c0 = blockIdx.y * 64, b = blockIdx.z;
  const float* xb = x + (long)b * C * NP;
#pragma unroll
  for (int i = 0; i < 4; ++i) {
    int s = i * 256 + t;
    int c = s >> 4, p4 = s & 15;
    float4 v = *(const float4*)&xb[(long)(c0 + c) * NP + p0 + p4 * 4];
    tile[c][p4 * 4 + 0] = v.x;
    tile[c][p4 * 4 + 1] = v.y;
    tile[c][p4 * 4 + 2] = v.z;
    tile[c][p4 * 4 + 3] = v.w;
  }
  __syncthreads();
  unsigned short* XTb = XT + (long)b * NP * 256;
#pragma unroll
  for (int i = 0; i < 2; ++i) {
    int s = i * 256 + t;
    int p = s >> 3, c8 = s & 7;
    unsigned short u[8];
#pragma unroll
    for (int e = 0; e < 8; ++e) u[e] = f2bf_rne(tile[c8 * 8 + e][p]);
    *(uint4*)&XTb[(long)(p0 + p) * 256 + c0 + c8 * 8] = *(const uint4*)u;
  }
}

// ---------------- all weights -> bf16 (one row per block) ------------------
__global__ __launch_bounds__(256) void cvt_w7(
    const float* __restrict__ l2, const float* __restrict__ q,
    const float* __restrict__ k,  const float* __restrict__ v,
    const float* __restrict__ qkv, const float* __restrict__ pw,
    unsigned short* __restrict__ W7)
{
  const int row = blockIdx.x;            // 0..2047
  const float* src; int r;
  if      (row <  256) { src = l2;  r = row; }
  else if (row <  512) { src = q;   r = row - 256; }
  else if (row <  768) { src = k;   r = row - 512; }
  else if (row < 1024) { src = v;   r = row - 768; }
  else if (row < 1792) { src = qkv; r = row - 1024; }
  else                 { src = pw;  r = row - 1792; }
  W7[row * 256 + threadIdx.x] = f2bf_rne(src[r * 256 + threadIdx.x]);
}

// ---------------- bf16 GEMM: W[M][256] x XT[pix][256]^T -> O[pix][M] bf16 --
__global__ __launch_bounds__(256) void gemm_bt(
    const unsigned short* __restrict__ W, const unsigned short* __restrict__ XT,
    unsigned short* __restrict__ O, int Mstride)
{
  __shared__ __align__(16) char smem[36864];
  unsigned short (*As)[40] = reinterpret_cast<unsigned short(*)[40]>(smem);
  unsigned short (*Bs)[40] = reinterpret_cast<unsigned short(*)[40]>(smem + 10240);

  const int t = threadIdx.x;
  const int lane = t & 63, wid = t >> 6;
  const int wm = wid >> 1, wn = wid & 1;
  const int l15 = lane & 15, l4 = lane >> 4;
  const int n0 = blockIdx.x * 128, m0 = blockIdx.y * 128;
  const unsigned short* XTb = XT + (long)blockIdx.z * NP * 256;
  unsigned short* Ob = O + (long)blockIdx.z * NP * Mstride;

  f32x4 acc[4][4];
#pragma unroll
  for (int i = 0; i < 4; ++i)
#pragma unroll
    for (int j = 0; j < 4; ++j) acc[i][j] = (f32x4){0.f, 0.f, 0.f, 0.f};

  for (int k0 = 0; k0 < 256; k0 += 32) {
#pragma unroll
    for (int i = 0; i < 2; ++i) {
      int s = i * 256 + t, r = s >> 2, kc = s & 3;
      *(uint4*)&As[r][kc * 8] =
          *(const uint4*)&W[(long)(m0 + r) * 256 + k0 + kc * 8];
    }
#pragma unroll
    for (int i = 0; i < 2; ++i) {
      int s = i * 256 + t, r = s >> 2, kc = s & 3;
      *(uint4*)&Bs[r][kc * 8] =
          *(const uint4*)&XTb[(long)(n0 + r) * 256 + k0 + kc * 8];
    }
    __syncthreads();

    bf16x8 af[4], bb[4];
#pragma unroll
    for (int mf = 0; mf < 4; ++mf)
      af[mf] = *(const bf16x8*)&As[wm * 64 + mf * 16 + l15][l4 * 8];
#pragma unroll
    for (int nf = 0; nf < 4; ++nf)
      bb[nf] = *(const bf16x8*)&Bs[wn * 64 + nf * 16 + l15][l4 * 8];
#pragma unroll
    for (int mf = 0; mf < 4; ++mf)
#pragma unroll
      for (int nf = 0; nf < 4; ++nf)
        acc[mf][nf] = __builtin_amdgcn_mfma_f32_16x16x32_bf16(
            af[mf], bb[nf], acc[mf][nf], 0, 0, 0);
    __syncthreads();
  }

  unsigned short* trw = (unsigned short*)smem + wid * 64 * 72;
#pragma unroll
  for (int mf = 0; mf < 4; ++mf)
#pragma unroll
    for (int nf = 0; nf < 4; ++nf) {
      unsigned u0 = (unsigned)f2bf_rne(acc[mf][nf][0]) |
                    ((unsigned)f2bf_rne(acc[mf][nf][1]) << 16);
      unsigned u1 = (unsigned)f2bf_rne(acc[mf][nf][2]) |
                    ((unsigned)f2bf_rne(acc[mf][nf][3]) << 16);
      uint2 uu; uu.x = u0; uu.y = u1;
      *(uint2*)&trw[(nf * 16 + l15) * 72 + mf * 16 + l4 * 4] = uu;
    }
  __syncthreads();

  const long pix = n0 + wn * 64 + lane;
  const long rowbase = pix * Mstride + m0 + wm * 64;
#pragma unroll
  for (int cc = 0; cc < 8; ++cc)
    *(uint4*)&Ob[rowbase + cc * 8] = *(const uint4*)&trw[lane * 72 + cc * 8];
}

// ---------------- bf16 GEMM, fp32 channel-major output (final pw) ----------
__global__ __launch_bounds__(256) void gemm_cf32(
    const unsigned short* __restrict__ W, const unsigned short* __restrict__ XT,
    float* __restrict__ Co)
{
  __shared__ unsigned short As[128][40];
  __shared__ unsigned short Bs[128][40];

  const int t = threadIdx.x;
  const int lane = t & 63, wid = t >> 6;
  const int wm = wid >> 1, wn = wid & 1;
  const int l15 = lane & 15, l4 = lane >> 4;
  const int n0 = blockIdx.x * 128, m0 = blockIdx.y * 128;
  const unsigned short* XTb = XT + (long)blockIdx.z * NP * 256;
  float* Cb = Co + (long)blockIdx.z * C * NP;

  f32x4 acc[4][4];
#pragma unroll
  for (int i = 0; i < 4; ++i)
#pragma unroll
    for (int j = 0; j < 4; ++j) acc[i][j] = (f32x4){0.f, 0.f, 0.f, 0.f};

  for (int k0 = 0; k0 < 256; k0 += 32) {
#pragma unroll
    for (int i = 0; i < 2; ++i) {
      int s = i * 256 + t, r = s >> 2, kc = s & 3;
      *(uint4*)&As[r][kc * 8] =
          *(const uint4*)&W[(long)(m0 + r) * 256 + k0 + kc * 8];
    }
#pragma unroll
    for (int i = 0; i < 2; ++i) {
      int s = i * 256 + t, r = s >> 2, kc = s & 3;
      *(uint4*)&Bs[r][kc * 8] =
          *(const uint4*)&XTb[(long)(n0 + r) * 256 + k0 + kc * 8];
    }
    __syncthreads();

    bf16x8 af[4], bb[4];
#pragma unroll
    for (int mf = 0; mf < 4; ++mf)
      af[mf] = *(const bf16x8*)&As[wm * 64 + mf * 16 + l15][l4 * 8];
#pragma unroll
    for (int nf = 0; nf < 4; ++nf)
      bb[nf] = *(const bf16x8*)&Bs[wn * 64 + nf * 16 + l15][l4 * 8];
#pragma unroll
    for (int mf = 0; mf < 4; ++mf)
#pragma unroll
      for (int nf = 0; nf < 4; ++nf)
        acc[mf][nf] = __builtin_amdgcn_mfma_f32_16x16x32_bf16(
            af[mf], bb[nf], acc[mf][nf], 0, 0, 0);
    __syncthreads();
  }

#pragma unroll
  for (int mf = 0; mf < 4; ++mf)
#pragma unroll
    for (int r = 0; r < 4; ++r) {
      int row = m0 + wm * 64 + mf * 16 + l4 * 4 + r;
#pragma unroll
      for (int nf = 0; nf < 4; ++nf) {
        int col = n0 + wn * 64 + nf * 16 + l15;
        Cb[(long)row * NP + col] = acc[mf][nf][r];
      }
    }
}

// ---------------- 3x3 neighborhood attention + BN + bias (pixel-major) -----
__global__ __launch_bounds__(256) void local_attn2(
    const unsigned short* __restrict__ GA,
    const float* __restrict__ rel_x, const float* __restrict__ rel_y,
    const float* __restrict__ bn2_g, const float* __restrict__ bn2_b,
    const float* __restrict__ bn2_m, const float* __restrict__ bn2_v,
    const float* __restrict__ l1_bias, float* __restrict__ localO)
{
  const int b = blockIdx.y, t = threadIdx.x;
  const int px = t & 31, ch = t >> 5;          // ch 0..7
  const int p = blockIdx.x * 32 + px;
  const unsigned short* Gb = GA + (long)b * NP * 1024;

  __shared__ float red[8][32][13];
  __shared__ float srel[256 * 3];
  __shared__ float sS[256], sO[256], sBias[256];

  if (t < 128) {
    srel[t * 3 + 0] = rel_x[t * 3 + 0];
    srel[t * 3 + 1] = rel_x[t * 3 + 1];
    srel[t * 3 + 2] = rel_x[t * 3 + 2];
  } else {
    int r = t - 128;
    srel[t * 3 + 0] = rel_y[r * 3 + 0];
    srel[t * 3 + 1] = rel_y[r * 3 + 1];
    srel[t * 3 + 2] = rel_y[r * 3 + 2];
  }
  {
    float s = bn2_g[t] * rsqrtf(bn2_v[t] + 1e-5f);
    sS[t] = s;
    sO[t] = bn2_b[t] - bn2_m[t] * s;
    sBias[t] = l1_bias[t];
  }

  const int h = p / 96, w = p % 96;
  int nof[9];
  float msk[9];
#pragma unroll
  for (int ky = 0; ky < 3; ++ky)
#pragma unroll
    for (int kx = 0; kx < 3; ++kx) {
      int j = ky * 3 + kx, hn = h + ky - 1, wn = w + kx - 1;
      bool v = (hn >= 0 && hn < 96 && wn >= 0 && wn < 96);
      nof[j] = v ? hn * 96 + wn : p;
      msk[j] = v ? 1.f : 0.f;
    }
  __syncthreads();

  float lg[9] = {0, 0, 0, 0, 0, 0, 0, 0, 0};
  float rq[3] = {0, 0, 0};
  const int c0 = ch * 32;
#pragma unroll
  for (int i = 0; i < 4; ++i) {
    const int c = c0 + i * 8;
    bf16x8 q8 = *(const bf16x8*)&Gb[(long)p * 1024 + 256 + c];
    float qv[8];
#pragma unroll
    for (int e = 0; e < 8; ++e) qv[e] = (float)q8[e];
#pragma unroll
    for (int j = 0; j < 9; ++j) {
      bf16x8 k8 = *(const bf16x8*)&Gb[(long)nof[j] * 1024 + 512 + c];
#pragma unroll
      for (int e = 0; e < 8; ++e) lg[j] += qv[e] * (float)k8[e];
    }
#pragma unroll
    for (int e = 0; e < 8; ++e) {
      const float* sr = &srel[(c + e) * 3];
      rq[0] += qv[e] * sr[0];
      rq[1] += qv[e] * sr[1];
      rq[2] += qv[e] * sr[2];
    }
  }
#pragma unroll
  for (int j = 0; j < 9; ++j) red[ch][px][j] = lg[j] * msk[j];
#pragma unroll
  for (int l = 0; l < 3; ++l) red[ch][px][9 + l] = rq[l];
  __syncthreads();

  float a[9];
  float mx = -1e30f;
#pragma unroll
  for (int j = 0; j < 9; ++j) {
    float v = 0.f;
#pragma unroll
    for (int u = 0; u < 8; ++u) v += red[u][px][j];
    float qxl = red[0][px][9 + j % 3] + red[1][px][9 + j % 3] +
                red[2][px][9 + j % 3] + red[3][px][9 + j % 3];
    float qyk = red[4][px][9 + j / 3] + red[5][px][9 + j / 3] +
                red[6][px][9 + j / 3] + red[7][px][9 + j / 3];
    a[j] = v + qxl + qyk;
    mx = fmaxf(mx, a[j]);
  }
  float sum = 0.f;
#pragma unroll
  for (int j = 0; j < 9; ++j) { a[j] = __expf(a[j] - mx); sum += a[j]; }
  const float inv = 1.f / sum;
  float am[9];
#pragma unroll
  for (int j = 0; j < 9; ++j) am[j] = a[j] * inv * msk[j];

#pragma unroll
  for (int i = 0; i < 4; ++i) {
    const int c = c0 + i * 8;
    bf16x8 l28 = *(const bf16x8*)&Gb[(long)p * 1024 + 0 + c];
    float o8[8] = {0, 0, 0, 0, 0, 0, 0, 0};
#pragma unroll
    for (int j = 0; j < 9; ++j) {
      bf16x8 v8 = *(const bf16x8*)&Gb[(long)nof[j] * 1024 + 768 + c];
#pragma unroll
      for (int e = 0; e < 8; ++e) o8[e] += am[j] * (float)v8[e];
    }
#pragma unroll
    for (int e = 0; e < 8; ++e) {
      const int cg = c + e;
      localO[((long)b * C + cg) * NP + p] =
          (float)l28[e] * sS[cg] + sO[cg] + o8[e] + sBias[cg];
    }
  }
}

// ---------------- 8x8 window attention via MFMA (GB [pix][768]) ------------
__global__ __launch_bounds__(64) void window_attn_mfma(
    const unsigned short* __restrict__ QKV,
    const float* __restrict__ rel_table, float* __restrict__ attnO)
{
  const int win = blockIdx.x, hd = blockIdx.y, b = blockIdx.z;
  const int wy = win / 12, wx = win % 12;
  const int lane = threadIdx.x;
  const int l15 = lane & 15, hi4 = lane >> 4;
  const int l31 = lane & 31, hi2 = lane >> 5;

  __shared__ float srpb[225];
  __shared__ __bf16 P[64][72];

  for (int i = lane; i < 225; i += 64) srpb[i] = rel_table[i * 16 + hd];

  const __bf16* base = (const __bf16*)QKV + (long)b * 9216 * 768;
  const int pixbase = (wy * 8) * 96 + wx * 8;

#define WPIX(i) (pixbase + ((i) >> 3) * 96 + ((i) & 7))

  bf16x8 kf[2], qf[2];
#pragma unroll
  for (int kt = 0; kt < 2; ++kt)
    kf[kt] = *(const bf16x8*)&base[(long)WPIX(32 * kt + l31) * 768 + 256 +
                                   hd * 16 + hi2 * 8];
#pragma unroll
  for (int qt = 0; qt < 2; ++qt)
    qf[qt] = *(const bf16x8*)&base[(long)WPIX(32 * qt + l31) * 768 +
                                   hd * 16 + hi2 * 8];

  bf16x8 vf[2];
#pragma unroll
  for (int kc = 0; kc < 2; ++kc)
#pragma unroll
    for (int j = 0; j < 8; ++j)
      vf[kc][j] = base[(long)WPIX(32 * kc + 8 * hi4 + j) * 768 + 512 +
                       hd * 16 + l15];

  f32x16 S[2][2];
#pragma unroll
  for (int kt = 0; kt < 2; ++kt)
#pragma unroll
    for (int qt = 0; qt < 2; ++qt)
#pragma unroll
      for (int r = 0; r < 16; ++r) S[kt][qt][r] = 0.f;

#pragma unroll
  for (int kt = 0; kt < 2; ++kt)
#pragma unroll
    for (int qt = 0; qt < 2; ++qt)
      S[kt][qt] = __builtin_amdgcn_mfma_f32_32x32x16_bf16(
          kf[kt], qf[qt], S[kt][qt], 0, 0, 0);

  __syncthreads();

  float mx[2] = {-1e30f, -1e30f};
#pragma unroll
  for (int kt = 0; kt < 2; ++kt)
#pragma unroll
    for (int r = 0; r < 16; ++r) {
      const int key = 32 * kt + (r & 3) + 8 * (r >> 2) + 4 * hi2;
      const int ky = key >> 3, kx = key & 7;
#pragma unroll
      for (int qt = 0; qt < 2; ++qt) {
        const int q = 32 * qt + l31;
        const int qy = q >> 3, qx = q & 7;
        float s = S[kt][qt][r] * 0.25f + srpb[(qy - ky + 7) * 15 + (qx - kx + 7)];
        S[kt][qt][r] = s;
        mx[qt] = fmaxf(mx[qt], s);
      }
    }
#pragma unroll
  for (int qt = 0; qt < 2; ++qt)
    mx[qt] = fmaxf(mx[qt], __shfl_xor(mx[qt], 32));

  float sum[2] = {0.f, 0.f};
#pragma unroll
  for (int kt = 0; kt < 2; ++kt)
#pragma unroll
    for (int qt = 0; qt < 2; ++qt)
#pragma unroll
      for (int r = 0; r < 16; ++r) {
        float e = __expf(S[kt][qt][r] - mx[qt]);
        S[kt][qt][r] = e;
        sum[qt] += e;
      }
#pragma unroll
  for (int qt = 0; qt < 2; ++qt) sum[qt] += __shfl_xor(sum[qt], 32);
  const float inv0 = 1.f / sum[0], inv1 = 1.f / sum[1];

#pragma unroll
  for (int qt = 0; qt < 2; ++qt) {
    const float inv = qt ? inv1 : inv0;
#pragma unroll
    for (int kt = 0; kt < 2; ++kt)
#pragma unroll
      for (int rq = 0; rq < 4; ++rq) {
        bf16x4 pk;
#pragma unroll
        for (int j = 0; j < 4; ++j) pk[j] = f2bf16(S[kt][qt][rq * 4 + j] * inv);
        *(bf16x4*)&P[32 * qt + l31][32 * kt + 8 * rq + 4 * hi2] = pk;
      }
  }
  __syncthreads();

  f32x4 o[4];
#pragma unroll
  for (int qt4 = 0; qt4 < 4; ++qt4) o[qt4] = (f32x4){0.f, 0.f, 0.f, 0.f};
#pragma unroll
  for (int kc = 0; kc < 2; ++kc)
#pragma unroll
    for (int qt4 = 0; qt4 < 4; ++qt4) {
      bf16x8 pf = *(const bf16x8*)&P[16 * qt4 + l15][32 * kc + 8 * hi4];
      o[qt4] = __builtin_amdgcn_mfma_f32_16x16x32_bf16(vf[kc], pf, o[qt4], 0, 0, 0);
    }

#pragma unroll
  for (int qt4 = 0; qt4 < 4; ++qt4)
#pragma unroll
    for (int r = 0; r < 4; ++r) {
      const int q = 16 * qt4 + l15;
      attnO[((long)b * C + hd * 16 + 4 * hi4 + r) * NP + WPIX(q)] = o[qt4][r];
    }
#undef WPIX
}

// ---------------- fused pools + combine + dw conv + BN (padded LDS) --------
// One block per (row-tile of 24, c, b).  All pad/reflect values materialized
// in LDS so pool and conv inner loops are branch-free.
// img : attn rows [r0-6, r0+31] as 38 slots x 105 stride; cols s=-3..99 at
//       slot s+3 (invalid -> -1e30, 96 -> dup of 94).
// img2: conv input rows [r0-3, r0+27] as 31 slots x 105 stride; zero-padded,
//       row/col 96 -> dup of 94 (computed via clamped source coords).
__global__ __launch_bounds__(256) void pool_dw3(
    const float* __restrict__ attn, const float* __restrict__ localO,
    const float* __restrict__ dww,
    const float* __restrict__ bnp_g, const float* __restrict__ bnp_b,
    const float* __restrict__ bnp_m, const float* __restrict__ bnp_v,
    float* __restrict__ dst)
{
  const int r0 = blockIdx.x * 24;
  const int c = blockIdx.y, b = blockIdx.z;
  const int t = threadIdx.x;

  __shared__ float img[38 * 105];
  __shared__ float img2[31 * 105];

  const float* A = attn + ((long)b * C + c) * NP;
  const float* L = localO + ((long)b * C + c) * NP;

  // ---- stage img (38 x 103 logical entries), pads materialized ----
  for (int idx = t; idx < 38 * 103; idx += 256) {
    const int j = idx / 103, k = idx % 103;
    const int R = r0 - 6 + j, s = k - 3;
    const bool valid = (R >= 0 && R <= 96 && s >= 0 && s <= 96);
    int Rc = (R == 96) ? 94 : R;
    Rc = min(max(Rc, 0), 95);
    int sc = (s == 96) ? 94 : s;
    sc = min(max(sc, 0), 95);
    const float v = A[Rc * 96 + sc];
    img[j * 105 + k] = valid ? v : -1e30f;
  }
  float wr[64];
#pragma unroll
  for (int i = 0; i < 64; ++i) wr[i] = dww[c * 64 + i];  // uniform -> SGPR
  __syncthreads();

  // ---- pools + combine -> img2 (31 x 103 logical entries) ----
  for (int idx = t; idx < 31 * 103; idx += 256) {
    const int j2 = idx / 103, k = idx % 103;
    const int R2 = r0 - 3 + j2, s = k - 3;
    const bool valid = (R2 >= 0 && R2 <= 96 && s >= 0 && s <= 96);
    int R2c = (R2 == 96) ? 94 : R2;
    R2c = min(max(R2c, 0), 95);
    int sc = (s == 96) ? 94 : s;
    sc = min(max(sc, 0), 95);
    const int jb = R2c - r0 + 6;      // img slot of row R2c
    const int kc = sc + 3;            // img col slot of col sc

    float mph = -1e30f, aph = 0.f, mpw = -1e30f, apw = 0.f;
#pragma unroll
    for (int i = 0; i < 8; ++i) {
      const float hv = img[(jb - 3 + i) * 105 + kc];
      mph = fmaxf(mph, hv);
      aph += (hv > -1e29f) ? hv : 0.f;
      const float wv = img[jb * 105 + kc - 3 + i];
      mpw = fmaxf(mpw, wv);
      apw += (wv > -1e29f) ? wv : 0.f;
    }
    const float val =
        mph + mpw + (aph + apw) * 0.125f + L[R2c * 96 + sc];
    img2[j2 * 105 + k] = valid ? val : 0.f;
  }
  __syncthreads();

  // ---- depthwise 8x8 conv + BN (branch-free) ----
  const float scl = bnp_g[c] * rsqrtf(bnp_v[c] + 1e-5f);
  const float off = bnp_b[c] - bnp_m[c] * scl;

#pragma unroll
  for (int ss = 0; ss < 2; ++ss) {
    const int seg = ss * 256 + t;
    if (seg >= 288) break;
    const int hh = seg / 12, w0 = (seg % 12) * 8;
    float acc[8] = {0, 0, 0, 0, 0, 0, 0, 0};
#pragma unroll
    for (int i = 0; i < 8; ++i) {
      const float* row = &img2[(hh + i) * 105 + w0];
      float win[15];
#pragma unroll
      for (int jj = 0; jj < 15; ++jj) win[jj] = row[jj];
#pragma unroll
      for (int j = 0; j < 8; ++j)
#pragma unroll
        for (int jj = 0; jj < 8; ++jj)
          acc[j] = fmaf(wr[i * 8 + jj], win[j + jj], acc[j]);
    }
    const long o = ((long)b * C + c) * NP + (r0 + hh) * 96 + w0;
#pragma unroll
    for (int j = 0; j < 8; ++j) dst[o + j] = acc[j] * scl + off;
  }
}

}  // namespace

extern "C" void kernel_launch(void* const* d_in, const int* in_sizes, int n_in,
                              void* d_out, int out_size, void* d_ws, size_t ws_size,
                              hipStream_t stream) {
  const float* x         = (const float*)d_in[0];
  const float* qkv_w     = (const float*)d_in[1];
  const float* l2_w      = (const float*)d_in[2];
  const float* bn2_g     = (const float*)d_in[3];
  const float* bn2_b     = (const float*)d_in[4];
  const float* bn2_m     = (const float*)d_in[5];
  const float* bn2_v     = (const float*)d_in[6];
  const float* wq        = (const float*)d_in[7];
  const float* wk        = (const float*)d_in[8];
  const float* wv        = (const float*)d_in[9];
  const float* rel_x     = (const float*)d_in[10];
  const float* rel_y     = (const float*)d_in[11];
  const float* l1_bias   = (const float*)d_in[12];
  const float* rel_table = (const float*)d_in[13];
  const float* dw_w      = (const float*)d_in[14];
  const float* bnp_g     = (const float*)d_in[15];
  const float* bnp_b     = (const float*)d_in[16];
  const float* bnp_m     = (const float*)d_in[17];
  const float* bnp_v     = (const float*)d_in[18];
  const float* pw_w      = (const float*)d_in[19];
  float* out = (float*)d_out;
  float* ws  = (float*)d_ws;

  unsigned short* GA     = (unsigned short*)ws;
  unsigned short* GB     = (unsigned short*)ws;
  float*          dwB    = ws;
  unsigned short* XT2    = (unsigned short*)(ws + 4718592);
  float*          localB = ws + 9437184;
  float*          attnB  = ws + 14155776;
  unsigned short* W7     = (unsigned short*)(ws + 20971520);
  unsigned short* XT     = (unsigned short*)(ws + 21233664);

  // 1. x -> XT bf16 [pix][256]
  xpose<<<dim3(144, 4, 2), 256, 0, stream>>>(x, XT);

  // 2. all weights -> W7 bf16
  cvt_w7<<<dim3(2048), 256, 0, stream>>>(l2_w, wq, wk, wv, qkv_w, pw_w, W7);

  // 3. [l2|qL|kL|vL] -> GA bf16 [pix][1024]
  gemm_bt<<<dim3(72, 8, 2), 256, 0, stream>>>(W7, XT, GA, 1024);

  // 4. neighborhood attention + BN + bias -> localB
  local_attn2<<<dim3(288, 2), 256, 0, stream>>>(GA, rel_x, rel_y, bn2_g, bn2_b,
                                                bn2_m, bn2_v, l1_bias, localB);

  // 5. qkv -> GB bf16 [pix][768] (over GA)
  gemm_bt<<<dim3(72, 6, 2), 256, 0, stream>>>(W7 + 1024 * 256, XT, GB, 768);

  // 6. window attention (MFMA) -> attnB
  window_attn_mfma<<<dim3(144, 16, 2), 64, 0, stream>>>(GB, rel_table, attnB);

  // 7. pools + combine + depthwise conv + BN -> dwB (padded LDS)
  pool_dw3<<<dim3(4, 256, 2), 256, 0, stream>>>(attnB, localB, dw_w, bnp_g,
                                                bnp_b, bnp_m, bnp_v, dwB);

  // 8. dwB -> XT2 bf16 [pix][256]
  xpose<<<dim3(144, 4, 2), 256, 0, stream>>>(dwB, XT2);

  // 9. pointwise GEMM -> out (fp32 channel-major)
  gemm_cf32<<<dim3(72, 2, 2), 256, 0, stream>>>(W7 + 1792 * 256, XT2, out);
}

// Round 7
// 174.257 us; speedup vs baseline: 3.3189x; 1.0213x over previous
//
#include <hip/hip_runtime.h>
#include <math.h>

// GlobalLocalAttention — round 6: float4-vectorized pool_dw4.
//
// Pipeline:
//  1. xpose:   x fp32 [b][256][NP] -> XT bf16 [b][NP][256]
//  2. cvt_w7:  all weights -> W7 bf16 [2048][256]
//  3. gemm_bt(W7[0:1024])    -> GA bf16 [b][NP][1024]
//  4. local_attn2(GA)        -> localB fp32 [b][256][NP]
//  5. gemm_bt(W7[1024:1792]) -> GB bf16 [b][NP][768]   (over GA, dead)
//  6. window_attn_mfma(GB)   -> attnB fp32 [b][256][NP]
//  7. pool_dw4 (pool+combine+dwconv+BN, f4-LDS) -> dwB fp32
//  8. xpose(dwB)             -> XT2 bf16 [b][NP][256]
//  9. gemm_cf32(W7[1792:2048], XT2) -> d_out fp32 [b][256][NP]

namespace {

constexpr int NP = 96 * 96;   // 9216
constexpr int C  = 256;

typedef __bf16 bf16x8 __attribute__((ext_vector_type(8)));
typedef float  f32x4  __attribute__((ext_vector_type(4)));
typedef float  f32x16 __attribute__((ext_vector_type(16)));
typedef __bf16 bf16x4 __attribute__((ext_vector_type(4)));

__device__ __forceinline__ unsigned short f2bf_rne(float f) {
  unsigned u = __float_as_uint(f);
  u += 0x7FFFu + ((u >> 16) & 1u);
  return (unsigned short)(u >> 16);
}
__device__ __forceinline__ __bf16 f2bf16(float f) {
  unsigned short s = f2bf_rne(f);
  return *(__bf16*)&s;
}

// ---------------- transpose: fp32 [c][pix] -> bf16 [pix][c] ----------------
__global__ __launch_bounds__(256) void xpose(
    const float* __restrict__ x, unsigned short* __restrict__ XT)
{
  __shared__ float tile[64][65];
  const int t = threadIdx.x;
  const int p0 = blockIdx.x * 64, c0 = blockIdx.y * 64, b = blockIdx.z;
  const float* xb = x + (long)b * C * NP;
#pragma unroll
  for (int i = 0; i < 4; ++i) {
    int s = i * 256 + t;
    int c = s >> 4, p4 = s & 15;
    float4 v = *(const float4*)&xb[(long)(c0 + c) * NP + p0 + p4 * 4];
    tile[c][p4 * 4 + 0] = v.x;
    tile[c][p4 * 4 + 1] = v.y;
    tile[c][p4 * 4 + 2] = v.z;
    tile[c][p4 * 4 + 3] = v.w;
  }
  __syncthreads();
  unsigned short* XTb = XT + (long)b * NP * 256;
#pragma unroll
  for (int i = 0; i < 2; ++i) {
    int s = i * 256 + t;
    int p = s >> 3, c8 = s & 7;
    unsigned short u[8];
#pragma unroll
    for (int e = 0; e < 8; ++e) u[e] = f2bf_rne(tile[c8 * 8 + e][p]);
    *(uint4*)&XTb[(long)(p0 + p) * 256 + c0 + c8 * 8] = *(const uint4*)u;
  }
}

// ---------------- all weights -> bf16 (one row per block) ------------------
__global__ __launch_bounds__(256) void cvt_w7(
    const float* __restrict__ l2, const float* __restrict__ q,
    const float* __restrict__ k,  const float* __restrict__ v,
    const float* __restrict__ qkv, const float* __restrict__ pw,
    unsigned short* __restrict__ W7)
{
  const int row = blockIdx.x;            // 0..2047
  const float* src; int r;
  if      (row <  256) { src = l2;  r = row; }
  else if (row <  512) { src = q;   r = row - 256; }
  else if (row <  768) { src = k;   r = row - 512; }
  else if (row < 1024) { src = v;   r = row - 768; }
  else if (row < 1792) { src = qkv; r = row - 1024; }
  else                 { src = pw;  r = row - 1792; }
  W7[row * 256 + threadIdx.x] = f2bf_rne(src[r * 256 + threadIdx.x]);
}

// ---------------- bf16 GEMM: W[M][256] x XT[pix][256]^T -> O[pix][M] bf16 --
__global__ __launch_bounds__(256) void gemm_bt(
    const unsigned short* __restrict__ W, const unsigned short* __restrict__ XT,
    unsigned short* __restrict__ O, int Mstride)
{
  __shared__ __align__(16) char smem[36864];
  unsigned short (*As)[40] = reinterpret_cast<unsigned short(*)[40]>(smem);
  unsigned short (*Bs)[40] = reinterpret_cast<unsigned short(*)[40]>(smem + 10240);

  const int t = threadIdx.x;
  const int lane = t & 63, wid = t >> 6;
  const int wm = wid >> 1, wn = wid & 1;
  const int l15 = lane & 15, l4 = lane >> 4;
  const int n0 = blockIdx.x * 128, m0 = blockIdx.y * 128;
  const unsigned short* XTb = XT + (long)blockIdx.z * NP * 256;
  unsigned short* Ob = O + (long)blockIdx.z * NP * Mstride;

  f32x4 acc[4][4];
#pragma unroll
  for (int i = 0; i < 4; ++i)
#pragma unroll
    for (int j = 0; j < 4; ++j) acc[i][j] = (f32x4){0.f, 0.f, 0.f, 0.f};

  for (int k0 = 0; k0 < 256; k0 += 32) {
#pragma unroll
    for (int i = 0; i < 2; ++i) {
      int s = i * 256 + t, r = s >> 2, kc = s & 3;
      *(uint4*)&As[r][kc * 8] =
          *(const uint4*)&W[(long)(m0 + r) * 256 + k0 + kc * 8];
    }
#pragma unroll
    for (int i = 0; i < 2; ++i) {
      int s = i * 256 + t, r = s >> 2, kc = s & 3;
      *(uint4*)&Bs[r][kc * 8] =
          *(const uint4*)&XTb[(long)(n0 + r) * 256 + k0 + kc * 8];
    }
    __syncthreads();

    bf16x8 af[4], bb[4];
#pragma unroll
    for (int mf = 0; mf < 4; ++mf)
      af[mf] = *(const bf16x8*)&As[wm * 64 + mf * 16 + l15][l4 * 8];
#pragma unroll
    for (int nf = 0; nf < 4; ++nf)
      bb[nf] = *(const bf16x8*)&Bs[wn * 64 + nf * 16 + l15][l4 * 8];
#pragma unroll
    for (int mf = 0; mf < 4; ++mf)
#pragma unroll
      for (int nf = 0; nf < 4; ++nf)
        acc[mf][nf] = __builtin_amdgcn_mfma_f32_16x16x32_bf16(
            af[mf], bb[nf], acc[mf][nf], 0, 0, 0);
    __syncthreads();
  }

  unsigned short* trw = (unsigned short*)smem + wid * 64 * 72;
#pragma unroll
  for (int mf = 0; mf < 4; ++mf)
#pragma unroll
    for (int nf = 0; nf < 4; ++nf) {
      unsigned u0 = (unsigned)f2bf_rne(acc[mf][nf][0]) |
                    ((unsigned)f2bf_rne(acc[mf][nf][1]) << 16);
      unsigned u1 = (unsigned)f2bf_rne(acc[mf][nf][2]) |
                    ((unsigned)f2bf_rne(acc[mf][nf][3]) << 16);
      uint2 uu; uu.x = u0; uu.y = u1;
      *(uint2*)&trw[(nf * 16 + l15) * 72 + mf * 16 + l4 * 4] = uu;
    }
  __syncthreads();

  const long pix = n0 + wn * 64 + lane;
  const long rowbase = pix * Mstride + m0 + wm * 64;
#pragma unroll
  for (int cc = 0; cc < 8; ++cc)
    *(uint4*)&Ob[rowbase + cc * 8] = *(const uint4*)&trw[lane * 72 + cc * 8];
}

// ---------------- bf16 GEMM, fp32 channel-major output (final pw) ----------
__global__ __launch_bounds__(256) void gemm_cf32(
    const unsigned short* __restrict__ W, const unsigned short* __restrict__ XT,
    float* __restrict__ Co)
{
  __shared__ unsigned short As[128][40];
  __shared__ unsigned short Bs[128][40];

  const int t = threadIdx.x;
  const int lane = t & 63, wid = t >> 6;
  const int wm = wid >> 1, wn = wid & 1;
  const int l15 = lane & 15, l4 = lane >> 4;
  const int n0 = blockIdx.x * 128, m0 = blockIdx.y * 128;
  const unsigned short* XTb = XT + (long)blockIdx.z * NP * 256;
  float* Cb = Co + (long)blockIdx.z * C * NP;

  f32x4 acc[4][4];
#pragma unroll
  for (int i = 0; i < 4; ++i)
#pragma unroll
    for (int j = 0; j < 4; ++j) acc[i][j] = (f32x4){0.f, 0.f, 0.f, 0.f};

  for (int k0 = 0; k0 < 256; k0 += 32) {
#pragma unroll
    for (int i = 0; i < 2; ++i) {
      int s = i * 256 + t, r = s >> 2, kc = s & 3;
      *(uint4*)&As[r][kc * 8] =
          *(const uint4*)&W[(long)(m0 + r) * 256 + k0 + kc * 8];
    }
#pragma unroll
    for (int i = 0; i < 2; ++i) {
      int s = i * 256 + t, r = s >> 2, kc = s & 3;
      *(uint4*)&Bs[r][kc * 8] =
          *(const uint4*)&XTb[(long)(n0 + r) * 256 + k0 + kc * 8];
    }
    __syncthreads();

    bf16x8 af[4], bb[4];
#pragma unroll
    for (int mf = 0; mf < 4; ++mf)
      af[mf] = *(const bf16x8*)&As[wm * 64 + mf * 16 + l15][l4 * 8];
#pragma unroll
    for (int nf = 0; nf < 4; ++nf)
      bb[nf] = *(const bf16x8*)&Bs[wn * 64 + nf * 16 + l15][l4 * 8];
#pragma unroll
    for (int mf = 0; mf < 4; ++mf)
#pragma unroll
      for (int nf = 0; nf < 4; ++nf)
        acc[mf][nf] = __builtin_amdgcn_mfma_f32_16x16x32_bf16(
            af[mf], bb[nf], acc[mf][nf], 0, 0, 0);
    __syncthreads();
  }

#pragma unroll
  for (int mf = 0; mf < 4; ++mf)
#pragma unroll
    for (int r = 0; r < 4; ++r) {
      int row = m0 + wm * 64 + mf * 16 + l4 * 4 + r;
#pragma unroll
      for (int nf = 0; nf < 4; ++nf) {
        int col = n0 + wn * 64 + nf * 16 + l15;
        Cb[(long)row * NP + col] = acc[mf][nf][r];
      }
    }
}

// ---------------- 3x3 neighborhood attention + BN + bias (pixel-major) -----
__global__ __launch_bounds__(256) void local_attn2(
    const unsigned short* __restrict__ GA,
    const float* __restrict__ rel_x, const float* __restrict__ rel_y,
    const float* __restrict__ bn2_g, const float* __restrict__ bn2_b,
    const float* __restrict__ bn2_m, const float* __restrict__ bn2_v,
    const float* __restrict__ l1_bias, float* __restrict__ localO)
{
  const int b = blockIdx.y, t = threadIdx.x;
  const int px = t & 31, ch = t >> 5;          // ch 0..7
  const int p = blockIdx.x * 32 + px;
  const unsigned short* Gb = GA + (long)b * NP * 1024;

  __shared__ float red[8][32][13];
  __shared__ float srel[256 * 3];
  __shared__ float sS[256], sO[256], sBias[256];

  if (t < 128) {
    srel[t * 3 + 0] = rel_x[t * 3 + 0];
    srel[t * 3 + 1] = rel_x[t * 3 + 1];
    srel[t * 3 + 2] = rel_x[t * 3 + 2];
  } else {
    int r = t - 128;
    srel[t * 3 + 0] = rel_y[r * 3 + 0];
    srel[t * 3 + 1] = rel_y[r * 3 + 1];
    srel[t * 3 + 2] = rel_y[r * 3 + 2];
  }
  {
    float s = bn2_g[t] * rsqrtf(bn2_v[t] + 1e-5f);
    sS[t] = s;
    sO[t] = bn2_b[t] - bn2_m[t] * s;
    sBias[t] = l1_bias[t];
  }

  const int h = p / 96, w = p % 96;
  int nof[9];
  float msk[9];
#pragma unroll
  for (int ky = 0; ky < 3; ++ky)
#pragma unroll
    for (int kx = 0; kx < 3; ++kx) {
      int j = ky * 3 + kx, hn = h + ky - 1, wn = w + kx - 1;
      bool v = (hn >= 0 && hn < 96 && wn >= 0 && wn < 96);
      nof[j] = v ? hn * 96 + wn : p;
      msk[j] = v ? 1.f : 0.f;
    }
  __syncthreads();

  float lg[9] = {0, 0, 0, 0, 0, 0, 0, 0, 0};
  float rq[3] = {0, 0, 0};
  const int c0 = ch * 32;
#pragma unroll
  for (int i = 0; i < 4; ++i) {
    const int c = c0 + i * 8;
    bf16x8 q8 = *(const bf16x8*)&Gb[(long)p * 1024 + 256 + c];
    float qv[8];
#pragma unroll
    for (int e = 0; e < 8; ++e) qv[e] = (float)q8[e];
#pragma unroll
    for (int j = 0; j < 9; ++j) {
      bf16x8 k8 = *(const bf16x8*)&Gb[(long)nof[j] * 1024 + 512 + c];
#pragma unroll
      for (int e = 0; e < 8; ++e) lg[j] += qv[e] * (float)k8[e];
    }
#pragma unroll
    for (int e = 0; e < 8; ++e) {
      const float* sr = &srel[(c + e) * 3];
      rq[0] += qv[e] * sr[0];
      rq[1] += qv[e] * sr[1];
      rq[2] += qv[e] * sr[2];
    }
  }
#pragma unroll
  for (int j = 0; j < 9; ++j) red[ch][px][j] = lg[j] * msk[j];
#pragma unroll
  for (int l = 0; l < 3; ++l) red[ch][px][9 + l] = rq[l];
  __syncthreads();

  float a[9];
  float mx = -1e30f;
#pragma unroll
  for (int j = 0; j < 9; ++j) {
    float v = 0.f;
#pragma unroll
    for (int u = 0; u < 8; ++u) v += red[u][px][j];
    float qxl = red[0][px][9 + j % 3] + red[1][px][9 + j % 3] +
                red[2][px][9 + j % 3] + red[3][px][9 + j % 3];
    float qyk = red[4][px][9 + j / 3] + red[5][px][9 + j / 3] +
                red[6][px][9 + j / 3] + red[7][px][9 + j / 3];
    a[j] = v + qxl + qyk;
    mx = fmaxf(mx, a[j]);
  }
  float sum = 0.f;
#pragma unroll
  for (int j = 0; j < 9; ++j) { a[j] = __expf(a[j] - mx); sum += a[j]; }
  const float inv = 1.f / sum;
  float am[9];
#pragma unroll
  for (int j = 0; j < 9; ++j) am[j] = a[j] * inv * msk[j];

#pragma unroll
  for (int i = 0; i < 4; ++i) {
    const int c = c0 + i * 8;
    bf16x8 l28 = *(const bf16x8*)&Gb[(long)p * 1024 + 0 + c];
    float o8[8] = {0, 0, 0, 0, 0, 0, 0, 0};
#pragma unroll
    for (int j = 0; j < 9; ++j) {
      bf16x8 v8 = *(const bf16x8*)&Gb[(long)nof[j] * 1024 + 768 + c];
#pragma unroll
      for (int e = 0; e < 8; ++e) o8[e] += am[j] * (float)v8[e];
    }
#pragma unroll
    for (int e = 0; e < 8; ++e) {
      const int cg = c + e;
      localO[((long)b * C + cg) * NP + p] =
          (float)l28[e] * sS[cg] + sO[cg] + o8[e] + sBias[cg];
    }
  }
}

// ---------------- 8x8 window attention via MFMA (GB [pix][768]) ------------
__global__ __launch_bounds__(64) void window_attn_mfma(
    const unsigned short* __restrict__ QKV,
    const float* __restrict__ rel_table, float* __restrict__ attnO)
{
  const int win = blockIdx.x, hd = blockIdx.y, b = blockIdx.z;
  const int wy = win / 12, wx = win % 12;
  const int lane = threadIdx.x;
  const int l15 = lane & 15, hi4 = lane >> 4;
  const int l31 = lane & 31, hi2 = lane >> 5;

  __shared__ float srpb[225];
  __shared__ __bf16 P[64][72];

  for (int i = lane; i < 225; i += 64) srpb[i] = rel_table[i * 16 + hd];

  const __bf16* base = (const __bf16*)QKV + (long)b * 9216 * 768;
  const int pixbase = (wy * 8) * 96 + wx * 8;

#define WPIX(i) (pixbase + ((i) >> 3) * 96 + ((i) & 7))

  bf16x8 kf[2], qf[2];
#pragma unroll
  for (int kt = 0; kt < 2; ++kt)
    kf[kt] = *(const bf16x8*)&base[(long)WPIX(32 * kt + l31) * 768 + 256 +
                                   hd * 16 + hi2 * 8];
#pragma unroll
  for (int qt = 0; qt < 2; ++qt)
    qf[qt] = *(const bf16x8*)&base[(long)WPIX(32 * qt + l31) * 768 +
                                   hd * 16 + hi2 * 8];

  bf16x8 vf[2];
#pragma unroll
  for (int kc = 0; kc < 2; ++kc)
#pragma unroll
    for (int j = 0; j < 8; ++j)
      vf[kc][j] = base[(long)WPIX(32 * kc + 8 * hi4 + j) * 768 + 512 +
                       hd * 16 + l15];

  f32x16 S[2][2];
#pragma unroll
  for (int kt = 0; kt < 2; ++kt)
#pragma unroll
    for (int qt = 0; qt < 2; ++qt)
#pragma unroll
      for (int r = 0; r < 16; ++r) S[kt][qt][r] = 0.f;

#pragma unroll
  for (int kt = 0; kt < 2; ++kt)
#pragma unroll
    for (int qt = 0; qt < 2; ++qt)
      S[kt][qt] = __builtin_amdgcn_mfma_f32_32x32x16_bf16(
          kf[kt], qf[qt], S[kt][qt], 0, 0, 0);

  __syncthreads();

  float mx[2] = {-1e30f, -1e30f};
#pragma unroll
  for (int kt = 0; kt < 2; ++kt)
#pragma unroll
    for (int r = 0; r < 16; ++r) {
      const int key = 32 * kt + (r & 3) + 8 * (r >> 2) + 4 * hi2;
      const int ky = key >> 3, kx = key & 7;
#pragma unroll
      for (int qt = 0; qt < 2; ++qt) {
        const int q = 32 * qt + l31;
        const int qy = q >> 3, qx = q & 7;
        float s = S[kt][qt][r] * 0.25f + srpb[(qy - ky + 7) * 15 + (qx - kx + 7)];
        S[kt][qt][r] = s;
        mx[qt] = fmaxf(mx[qt], s);
      }
    }
#pragma unroll
  for (int qt = 0; qt < 2; ++qt)
    mx[qt] = fmaxf(mx[qt], __shfl_xor(mx[qt], 32));

  float sum[2] = {0.f, 0.f};
#pragma unroll
  for (int kt = 0; kt < 2; ++kt)
#pragma unroll
    for (int qt = 0; qt < 2; ++qt)
#pragma unroll
      for (int r = 0; r < 16; ++r) {
        float e = __expf(S[kt][qt][r] - mx[qt]);
        S[kt][qt][r] = e;
        sum[qt] += e;
      }
#pragma unroll
  for (int qt = 0; qt < 2; ++qt) sum[qt] += __shfl_xor(sum[qt], 32);
  const float inv0 = 1.f / sum[0], inv1 = 1.f / sum[1];

#pragma unroll
  for (int qt = 0; qt < 2; ++qt) {
    const float inv = qt ? inv1 : inv0;
#pragma unroll
    for (int kt = 0; kt < 2; ++kt)
#pragma unroll
      for (int rq = 0; rq < 4; ++rq) {
        bf16x4 pk;
#pragma unroll
        for (int j = 0; j < 4; ++j) pk[j] = f2bf16(S[kt][qt][rq * 4 + j] * inv);
        *(bf16x4*)&P[32 * qt + l31][32 * kt + 8 * rq + 4 * hi2] = pk;
      }
  }
  __syncthreads();

  f32x4 o[4];
#pragma unroll
  for (int qt4 = 0; qt4 < 4; ++qt4) o[qt4] = (f32x4){0.f, 0.f, 0.f, 0.f};
#pragma unroll
  for (int kc = 0; kc < 2; ++kc)
#pragma unroll
    for (int qt4 = 0; qt4 < 4; ++qt4) {
      bf16x8 pf = *(const bf16x8*)&P[16 * qt4 + l15][32 * kc + 8 * hi4];
      o[qt4] = __builtin_amdgcn_mfma_f32_16x16x32_bf16(vf[kc], pf, o[qt4], 0, 0, 0);
    }

#pragma unroll
  for (int qt4 = 0; qt4 < 4; ++qt4)
#pragma unroll
    for (int r = 0; r < 4; ++r) {
      const int q = 16 * qt4 + l15;
      attnO[((long)b * C + hd * 16 + 4 * hi4 + r) * NP + WPIX(q)] = o[qt4][r];
    }
#undef WPIX
}

// ---------------- fused pools + combine + dw conv + BN (f4 LDS) ------------
// One block per (row-tile of 24, c, b).
// img : rows j=0..37 (R=r0-6+j), col slot = s+8 (s in -8..103), stride 112.
//       entry = valid(R,s) ? A[reflect] : -1e30.
// img2: rows j2=0..30 (R2=r0-3+j2), col slot = w'+4 (w' in -4..99), stride 108.
//       entry = valid ? pool(R2,w')+L : 0.
__global__ __launch_bounds__(256) void pool_dw4(
    const float* __restrict__ attn, const float* __restrict__ localO,
    const float* __restrict__ dww,
    const float* __restrict__ bnp_g, const float* __restrict__ bnp_b,
    const float* __restrict__ bnp_m, const float* __restrict__ bnp_v,
    float* __restrict__ dst)
{
  const int r0 = blockIdx.x * 24;
  const int c = blockIdx.y, b = blockIdx.z;
  const int t = threadIdx.x;

  __shared__ float img[38 * 112];
  __shared__ float img2[31 * 108];

  const float* A = attn + ((long)b * C + c) * NP;
  const float* L = localO + ((long)b * C + c) * NP;

  // ---- stage img: 38 rows x 28 float4 groups ----
  for (int idx = t; idx < 38 * 28; idx += 256) {
    const int j = idx / 28, k = idx % 28;
    const int R = r0 - 6 + j;
    const bool rv = (R >= 0 && R <= 96);
    const int Rc = (R == 96) ? 94 : (rv ? R : 0);
    const int s0 = 4 * k - 8;
    float4 v;
    if (rv && s0 >= 0 && s0 <= 92) {
      v = *(const float4*)&A[Rc * 96 + s0];
    } else if (rv && s0 == 96) {
      v.x = A[Rc * 96 + 94]; v.y = -1e30f; v.z = -1e30f; v.w = -1e30f;
    } else {
      v.x = -1e30f; v.y = -1e30f; v.z = -1e30f; v.w = -1e30f;
    }
    *(float4*)&img[j * 112 + 4 * k] = v;
  }
  float wr[64];
#pragma unroll
  for (int i = 0; i < 64; ++i) wr[i] = dww[c * 64 + i];  // uniform -> SGPR
  __syncthreads();

  // ---- pools + combine -> img2: 31 rows x 26 float4 groups ----
  for (int idx = t; idx < 31 * 26; idx += 256) {
    const int j2 = idx / 26, g = idx % 26;
    const int R2 = r0 - 3 + j2;
    const bool rv = (R2 >= 0 && R2 <= 96);
    const int R2c = (R2 == 96) ? 94 : (rv ? R2 : 0);
    const int jb = R2c - r0 + 6;          // img row slot
    float4 out;
    if (!rv || g == 0) {
      out.x = 0.f; out.y = 0.f; out.z = 0.f; out.w = 0.f;
    } else if (g < 25) {
      // bulk: w' = 4g-4 .. 4g-1 (all direct, no reflect within [0,95])
      float mph[4] = {-1e30f, -1e30f, -1e30f, -1e30f};
      float aph[4] = {0.f, 0.f, 0.f, 0.f};
#pragma unroll
      for (int i = 0; i < 8; ++i) {
        float4 hv = *(const float4*)&img[(jb - 3 + i) * 112 + 4 * g + 4];
        const float h4[4] = {hv.x, hv.y, hv.z, hv.w};
#pragma unroll
        for (int d = 0; d < 4; ++d) {
          mph[d] = fmaxf(mph[d], h4[d]);
          aph[d] += (h4[d] > -1e29f) ? h4[d] : 0.f;
        }
      }
      float r[12];
      {
        float4 a0 = *(const float4*)&img[jb * 112 + 4 * g];
        float4 a1 = *(const float4*)&img[jb * 112 + 4 * g + 4];
        float4 a2 = *(const float4*)&img[jb * 112 + 4 * g + 8];
        r[0] = a0.x; r[1] = a0.y; r[2] = a0.z; r[3] = a0.w;
        r[4] = a1.x; r[5] = a1.y; r[6] = a1.z; r[7] = a1.w;
        r[8] = a2.x; r[9] = a2.y; r[10] = a2.z; r[11] = a2.w;
      }
      float4 L4 = *(const float4*)&L[R2c * 96 + 4 * g - 4];
      const float l4[4] = {L4.x, L4.y, L4.z, L4.w};
      float o4[4];
#pragma unroll
      for (int d = 0; d < 4; ++d) {
        float mpw = -1e30f, apw = 0.f;
#pragma unroll
        for (int i = 0; i < 8; ++i) {
          const float wv = r[d + 1 + i];
          mpw = fmaxf(mpw, wv);
          apw += (wv > -1e29f) ? wv : 0.f;
        }
        o4[d] = mph[d] + mpw + (aph[d] + apw) * 0.125f + l4[d];
      }
      out.x = o4[0]; out.y = o4[1]; out.z = o4[2]; out.w = o4[3];
    } else {
      // g == 25: only w'=96 valid = dup of out col 94
      float mph = -1e30f, aph = 0.f;
#pragma unroll
      for (int i = 0; i < 8; ++i) {
        const float hv = img[(jb - 3 + i) * 112 + 102];   // col 94
        mph = fmaxf(mph, hv);
        aph += (hv > -1e29f) ? hv : 0.f;
      }
      float mpw = -1e30f, apw = 0.f;
#pragma unroll
      for (int i = 0; i < 8; ++i) {
        const float wv = img[jb * 112 + 99 + i];          // cols 91..98
        mpw = fmaxf(mpw, wv);
        apw += (wv > -1e29f) ? wv : 0.f;
      }
      out.x = mph + mpw + (aph + apw) * 0.125f + L[R2c * 96 + 94];
      out.y = 0.f; out.z = 0.f; out.w = 0.f;
    }
    *(float4*)&img2[j2 * 108 + 4 * g] = out;
  }
  __syncthreads();

  // ---- depthwise 8x8 conv + BN (f4 LDS reads, f4 stores) ----
  const float scl = bnp_g[c] * rsqrtf(bnp_v[c] + 1e-5f);
  const float off = bnp_b[c] - bnp_m[c] * scl;

#pragma unroll
  for (int ss = 0; ss < 2; ++ss) {
    const int seg = ss * 256 + t;
    if (seg >= 288) break;
    const int hh = seg / 12, w0 = (seg % 12) * 8;
    float acc[8] = {0, 0, 0, 0, 0, 0, 0, 0};
#pragma unroll
    for (int i = 0; i < 8; ++i) {
      const float* row = &img2[(hh + i) * 108 + w0];
      float win16[16];
      {
        float4 a0 = *(const float4*)&row[0];
        float4 a1 = *(const float4*)&row[4];
        float4 a2 = *(const float4*)&row[8];
        float4 a3 = *(const float4*)&row[12];
        win16[0] = a0.x;  win16[1] = a0.y;  win16[2] = a0.z;  win16[3] = a0.w;
        win16[4] = a1.x;  win16[5] = a1.y;  win16[6] = a1.z;  win16[7] = a1.w;
        win16[8] = a2.x;  win16[9] = a2.y;  win16[10] = a2.z; win16[11] = a2.w;
        win16[12] = a3.x; win16[13] = a3.y; win16[14] = a3.z; win16[15] = a3.w;
      }
#pragma unroll
      for (int j = 0; j < 8; ++j)
#pragma unroll
        for (int jj = 0; jj < 8; ++jj)
          acc[j] = fmaf(wr[i * 8 + jj], win16[1 + j + jj], acc[j]);
    }
    float4 s0, s1;
    s0.x = acc[0] * scl + off; s0.y = acc[1] * scl + off;
    s0.z = acc[2] * scl + off; s0.w = acc[3] * scl + off;
    s1.x = acc[4] * scl + off; s1.y = acc[5] * scl + off;
    s1.z = acc[6] * scl + off; s1.w = acc[7] * scl + off;
    float* o = dst + ((long)b * C + c) * NP + (r0 + hh) * 96 + w0;
    *(float4*)o = s0;
    *((float4*)o + 1) = s1;
  }
}

}  // namespace

extern "C" void kernel_launch(void* const* d_in, const int* in_sizes, int n_in,
                              void* d_out, int out_size, void* d_ws, size_t ws_size,
                              hipStream_t stream) {
  const float* x         = (const float*)d_in[0];
  const float* qkv_w     = (const float*)d_in[1];
  const float* l2_w      = (const float*)d_in[2];
  const float* bn2_g     = (const float*)d_in[3];
  const float* bn2_b     = (const float*)d_in[4];
  const float* bn2_m     = (const float*)d_in[5];
  const float* bn2_v     = (const float*)d_in[6];
  const float* wq        = (const float*)d_in[7];
  const float* wk        = (const float*)d_in[8];
  const float* wv        = (const float*)d_in[9];
  const float* rel_x     = (const float*)d_in[10];
  const float* rel_y     = (const float*)d_in[11];
  const float* l1_bias   = (const float*)d_in[12];
  const float* rel_table = (const float*)d_in[13];
  const float* dw_w      = (const float*)d_in[14];
  const float* bnp_g     = (const float*)d_in[15];
  const float* bnp_b     = (const float*)d_in[16];
  const float* bnp_m     = (const float*)d_in[17];
  const float* bnp_v     = (const float*)d_in[18];
  const float* pw_w      = (const float*)d_in[19];
  float* out = (float*)d_out;
  float* ws  = (float*)d_ws;

  unsigned short* GA     = (unsigned short*)ws;
  unsigned short* GB     = (unsigned short*)ws;
  float*          dwB    = ws;
  unsigned short* XT2    = (unsigned short*)(ws + 4718592);
  float*          localB = ws + 9437184;
  float*          attnB  = ws + 14155776;
  unsigned short* W7     = (unsigned short*)(ws + 20971520);
  unsigned short* XT     = (unsigned short*)(ws + 21233664);

  // 1. x -> XT bf16 [pix][256]
  xpose<<<dim3(144, 4, 2), 256, 0, stream>>>(x, XT);

  // 2. all weights -> W7 bf16
  cvt_w7<<<dim3(2048), 256, 0, stream>>>(l2_w, wq, wk, wv, qkv_w, pw_w, W7);

  // 3. [l2|qL|kL|vL] -> GA bf16 [pix][1024]
  gemm_bt<<<dim3(72, 8, 2), 256, 0, stream>>>(W7, XT, GA, 1024);

  // 4. neighborhood attention + BN + bias -> localB
  local_attn2<<<dim3(288, 2), 256, 0, stream>>>(GA, rel_x, rel_y, bn2_g, bn2_b,
                                                bn2_m, bn2_v, l1_bias, localB);

  // 5. qkv -> GB bf16 [pix][768] (over GA)
  gemm_bt<<<dim3(72, 6, 2), 256, 0, stream>>>(W7 + 1024 * 256, XT, GB, 768);

  // 6. window attention (MFMA) -> attnB
  window_attn_mfma<<<dim3(144, 16, 2), 64, 0, stream>>>(GB, rel_table, attnB);

  // 7. pools + combine + depthwise conv + BN -> dwB (f4 LDS)
  pool_dw4<<<dim3(4, 256, 2), 256, 0, stream>>>(attnB, localB, dw_w, bnp_g,
                                                bnp_b, bnp_m, bnp_v, dwB);

  // 8. dwB -> XT2 bf16 [pix][256]
  xpose<<<dim3(144, 4, 2), 256, 0, stream>>>(dwB, XT2);

  // 9. pointwise GEMM -> out (fp32 channel-major)
  gemm_cf32<<<dim3(72, 2, 2), 256, 0, stream>>>(W7 + 1792 * 256, XT2, out);
}